// Round 6
// baseline (859.285 us; speedup 1.0000x reference)
//
#include <hip/hip_runtime.h>
#include <math.h>

#define N_TOK 131072
#define N_E   1024
#define E_DIM 64
#define BETA  0.4

// d_out layout (float32, concatenated in return order):
#define ZQ_OFF   0
#define LOSS_OFF 8388608
#define IDX_OFF  8388609
#define PERP_OFF 8519681

// d_ws usage: 256 doubles (per-block sum_sq partials). Nothing needs init.
typedef _Float16 f16x8 __attribute__((ext_vector_type(8)));
typedef float f32x4  __attribute__((ext_vector_type(4)));
typedef unsigned long long u64;

__device__ __forceinline__ unsigned med3u(unsigned a, unsigned b, unsigned c) {
    unsigned d;
    asm("v_med3_u32 %0, %1, %2, %3" : "=v"(d) : "v"(a), "v"(b), "v"(c));
    return d;
}

// ONE persistent kernel: 256 blocks x 1024 threads (1 block/CU, 16 waves).
// Per block: COALESCED frag of codebook->LDS fp16 (x1024), c2s from the LDS
// frags (fp16 precision suffices for the screen; error <<margin), fp16 MFMA
// screen sweep, top-3 route (settled / 2-cand / full) into LDS lists, settled
// epilogue, in-block exact fixups with WAVE-UNIFORM cb access (R4-proven
// pattern; R5's code-per-lane cb reads were the 170us regression).
__global__ __launch_bounds__(1024, 4) void vq_all(
    const float* __restrict__ z, const float* __restrict__ cb,
    double* __restrict__ slots, float margin_u, float* __restrict__ out) {

    __shared__ __align__(16) unsigned char sbuf[131072];  // frags; reused by fixB
    __shared__ __align__(8)  unsigned short c2s[N_E];     // fp16(-512*c2)
    __shared__ int   best_s[512];
    __shared__ unsigned char flag_s[512];
    __shared__ unsigned listA[512];        // (tl<<20)|(e1<<10)|e2
    __shared__ unsigned short listB[512];  // tl
    __shared__ int cntA, cntB;
    __shared__ double wred[16], dredA[16], dredB[16];

    const int tid  = threadIdx.x;
    const int lane = tid & 63;
    const int wid  = tid >> 6;
    const int col  = lane & 15;
    const int quad = lane >> 4;
    const int blk_tok0 = blockIdx.x * 512;
    const int wave_tok0 = blk_tok0 + wid * 32;

    if (tid == 0) { cntA = 0; cntB = 0; }

    // z fragment loads first (HBM latency overlaps frag phase)
    float4 zl[2][4];
#pragma unroll
    for (int m = 0; m < 2; ++m) {
        const float* zr = z + (size_t)(wave_tok0 + m * 16 + col) * E_DIM + quad * 8;
#pragma unroll
        for (int kc = 0; kc < 2; ++kc) {
            zl[m][kc * 2]     = *(const float4*)(zr + kc * 32);
            zl[m][kc * 2 + 1] = *(const float4*)(zr + kc * 32 + 4);
        }
    }

    // frag: COALESCED cb read (contiguous float4 per thread), scattered 8B
    // LDS write via inverse layout map. Identical fp16 values to rounds 1-5.
    {
        const float4* cb4 = (const float4*)cb;
#pragma unroll
        for (int r = 0; r < 16; ++r) {
            const int ft = r * 1024 + tid;        // float4 index, 16384 total
            const float4 v = cb4[ft];
            const int code = ft >> 4;
            const int k0   = (ft & 15) * 4;
            const int cc = ((code >> 4) << 1) | (k0 >> 5);
            const int l  = (((k0 >> 3) & 3) << 4) | (code & 15);
            const int dst = (cc << 9) | (l << 3) | (k0 & 7);   // short index
            union { _Float16 h[4]; uint2 u; } pk;
            pk.h[0] = (_Float16)(v.x * 1024.0f);
            pk.h[1] = (_Float16)(v.y * 1024.0f);
            pk.h[2] = (_Float16)(v.z * 1024.0f);
            pk.h[3] = (_Float16)(v.w * 1024.0f);
            *(uint2*)(sbuf + dst * 2) = pk.u;
        }
    }
    __syncthreads();   // frags visible

    // c2s from LDS frags: thread = code; s = sum (1024c)^2 in f32;
    // stored fp16(-s/2048) == fp16(-512*c2) + bounded error (<<margin).
    {
        const int code = tid;
        const int cc0 = (code >> 4) << 1;
        const int c15 = code & 15;
        float s = 0.f;
#pragma unroll
        for (int half = 0; half < 2; ++half)
#pragma unroll
            for (int lv = 0; lv < 4; ++lv) {
                const int off = (((cc0 + half) << 9) |
                                 (((lv << 4) | c15) << 3)) * 2;
                union { uint4 u; _Float16 h[8]; } b;
                b.u = *(const uint4*)(sbuf + off);
#pragma unroll
                for (int j = 0; j < 8; ++j) {
                    float f = (float)b.h[j];
                    s = fmaf(f, f, s);
                }
            }
        union { _Float16 h; unsigned short u; } q;
        q.h = (_Float16)(s * (-1.0f / 2048.0f));
        c2s[tid] = q.u;
    }

    // A fragments
    f16x8 Ah[2][2];
#pragma unroll
    for (int m = 0; m < 2; ++m)
#pragma unroll
        for (int kc = 0; kc < 2; ++kc) {
            float4 u0 = zl[m][kc * 2], u1 = zl[m][kc * 2 + 1];
            f16x8 a;
            a[0] = (_Float16)u0.x; a[1] = (_Float16)u0.y;
            a[2] = (_Float16)u0.z; a[3] = (_Float16)u0.w;
            a[4] = (_Float16)u1.x; a[5] = (_Float16)u1.y;
            a[6] = (_Float16)u1.z; a[7] = (_Float16)u1.w;
            Ah[m][kc] = a;
        }

    // top-3 packed-key MAX tracker
    unsigned k1[2][4], k2[2][4], k3[2][4];
#pragma unroll
    for (int m = 0; m < 2; ++m)
#pragma unroll
        for (int r = 0; r < 4; ++r) { k1[m][r] = 0u; k2[m][r] = 0u; k3[m][r] = 0u; }

    __syncthreads();   // c2s complete

    // sweep: u'' = 1024*dot - 512*c2 + 64 > 0; key = (bits&~63)|(63-cl)
#pragma unroll 4
    for (int cl = 0; cl < 64; ++cl) {
        const unsigned char* bp = sbuf + cl * 2048 + lane * 16;
        union { uint4 u; f16x8 v; } b0, b1;
        b0.u = *(const uint4*)(bp);
        b1.u = *(const uint4*)(bp + 1024);
        union { unsigned short us; _Float16 h; } cv;
        cv.us = c2s[cl * 16 + col];
        const float ch = 64.0f + (float)cv.h;
        const f32x4 cinit = {ch, ch, ch, ch};
        const unsigned ctag = (unsigned)(63 - cl);
#pragma unroll
        for (int m = 0; m < 2; ++m) {
            f32x4 acc = __builtin_amdgcn_mfma_f32_16x16x32_f16(
                Ah[m][0], b0.v, cinit, 0, 0, 0);
            acc = __builtin_amdgcn_mfma_f32_16x16x32_f16(
                Ah[m][1], b1.v, acc, 0, 0, 0);
#pragma unroll
            for (int r = 0; r < 4; ++r) {
                unsigned key = (__float_as_uint(acc[r]) & 0xFFFFFFC0u) | ctag;
                unsigned t1 = min(k1[m][r], key);
                k3[m][r] = med3u(k2[m][r], k3[m][r], t1);
                k2[m][r] = med3u(k1[m][r], k2[m][r], key);
                k1[m][r] = max(k1[m][r], key);
            }
        }
    }

    // merge + route into LDS lists (validated R4/R5)
#pragma unroll 1
    for (int m = 0; m < 2; ++m) {
#pragma unroll 1
        for (int r = 0; r < 4; ++r) {
            const unsigned l1 = k1[m][r], l2 = k2[m][r], l3 = k3[m][r];
            unsigned g1 = l1, g2 = l2, g3 = l3;
#pragma unroll
            for (int d = 1; d < 16; d <<= 1) {
                unsigned p1 = __shfl_xor(g1, d, 64);
                unsigned p2 = __shfl_xor(g2, d, 64);
                unsigned p3 = __shfl_xor(g3, d, 64);
                unsigned t1 = min(g1, p1);
                g3 = med3u(g2, g3, t1);
                g2 = med3u(g1, g2, p1);
                g1 = max(g1, p1);
                g3 = med3u(g2, g3, p2);
                g2 = max(g2, p2);
                g3 = med3u(g2, g3, p3);
            }
            u64 bal1 = __ballot((l1 == g1) || (l2 == g1) || (l3 == g1));
            u64 bal2 = __ballot((l1 == g2) || (l2 == g2) || (l3 == g2));
            if (col == 0) {
                const int tl = wid * 32 + m * 16 + quad * 4 + r;
                unsigned m1 = (unsigned)((bal1 >> (quad * 16)) & 0xFFFFu);
                int c1 = __ffs(m1) - 1;
                int bbest = (63 - (int)(g1 & 63u)) * 16 + c1;
                float v1 = __uint_as_float(g1 & 0xFFFFFFC0u);
                float v2 = __uint_as_float(g2 & 0xFFFFFFC0u);
                float v3 = __uint_as_float(g3 & 0xFFFFFFC0u);
                int typ = 0, bsec = 0;
                if (v1 - v2 < margin_u) {
                    if (v1 - v3 < margin_u) typ = 2;
                    else {
                        unsigned m2 = (unsigned)((bal2 >> (quad * 16)) & 0xFFFFu);
                        if (g2 == g1) m2 &= ~(1u << c1);
                        if (__popc(m2) == 1) {
                            bsec = (63 - (int)(g2 & 63u)) * 16 + (__ffs(m2) - 1);
                            typ = 1;
                        } else typ = 2;
                    }
                }
                best_s[tl] = bbest;
                flag_s[tl] = typ ? 1 : 0;
                if (typ == 1) {
                    int pos = atomicAdd(&cntA, 1);
                    listA[pos] = ((unsigned)tl << 20) |
                                 ((unsigned)bbest << 10) | (unsigned)bsec;
                } else if (typ == 2) {
                    int pos = atomicAdd(&cntB, 1);
                    listB[pos] = (unsigned short)tl;
                }
            }
        }
    }

    // settled epilogue: coalesced z_q / loss partials (own-wave tokens only)
    {
        const int sub = lane & 15, grp = lane >> 4;
        double dl = 0.0;
        const float4* zrow = (const float4*)z;
        const float4* crow = (const float4*)cb;
        float4* qrow = (float4*)(out + ZQ_OFF);
#pragma unroll
        for (int p = 0; p < 8; ++p) {
            int tl = wid * 32 + p * 4 + grp;
            if (!flag_s[tl]) {
                int n = blk_tok0 + tl;
                float4 z4 = zrow[(size_t)n * 16 + sub];
                float4 c4 = crow[(size_t)best_s[tl] * 16 + sub];
                float dx = c4.x - z4.x, dy = c4.y - z4.y;
                float dz = c4.z - z4.z, dw = c4.w - z4.w;
                float4 q;
                q.x = z4.x + dx; q.y = z4.y + dy;
                q.z = z4.z + dz; q.w = z4.w + dw;
                qrow[(size_t)n * 16 + sub] = q;
                dl += (double)dx * dx + (double)dy * dy
                    + (double)dz * dz + (double)dw * dw;
            }
        }
#pragma unroll
        for (int off = 32; off > 0; off >>= 1)
            dl += __shfl_down(dl, off, 64);
        if (lane == 0) wred[wid] = dl;
    }

    __syncthreads();   // lists final; sbuf free for reuse
    const int nA = cntA, nB = cntB;

    // ---- fix-A: 2-candidate exact, thread-per-entry, float4 z loads ----
    {
        double da = 0.0;
        for (int t = tid; t < nA; t += 1024) {
            const unsigned ent = listA[t];
            const int tl = (int)(ent >> 20);
            const int e1 = (int)((ent >> 10) & 1023u);
            const int e2 = (int)(ent & 1023u);
            const int n  = blk_tok0 + tl;
            const float4* zp4 = (const float4*)(z + (size_t)n * E_DIM);
            float4 z4[16];
#pragma unroll
            for (int k = 0; k < 16; ++k) z4[k] = zp4[k];
            const float* zf = (const float*)z4;
            float r8[8];
#pragma unroll
            for (int j = 0; j < 8; ++j) r8[j] = __fmul_rn(zf[j], zf[j]);
#pragma unroll
            for (int i = 8; i < 64; i += 8)
#pragma unroll
                for (int j = 0; j < 8; ++j)
                    r8[j] = __fadd_rn(r8[j], __fmul_rn(zf[i + j], zf[i + j]));
            float z2 = __fadd_rn(
                __fadd_rn(__fadd_rn(r8[0], r8[1]), __fadd_rn(r8[2], r8[3])),
                __fadd_rn(__fadd_rn(r8[4], r8[5]), __fadd_rn(r8[6], r8[7])));
            u64 bk = ~0ull;
#pragma unroll
            for (int c = 0; c < 2; ++c) {
                const int e = c ? e2 : e1;
                const float* cp = cb + (size_t)e * E_DIM;
                double cs = 0.0, mm = 0.0;
#pragma unroll
                for (int k = 0; k < E_DIM; ++k) {
                    double cc = (double)cp[k];
                    cs = fma(cc, cc, cs);
                    mm = fma((double)zf[k], cc, mm);
                }
                float d = __fsub_rn(__fadd_rn(z2, (float)cs),
                                    __fmul_rn(2.0f, (float)mm));
                u64 key = ((u64)__float_as_uint(d) << 32) | (unsigned)e;
                if (key < bk) bk = key;
            }
            const int best = (int)(bk & 0xffffffffull);
            const float4* cp4 = (const float4*)(cb + (size_t)best * E_DIM);
            float4* qp = (float4*)(out + ZQ_OFF + (size_t)n * E_DIM);
            double dd = 0.0;
#pragma unroll
            for (int k = 0; k < 16; ++k) {
                float4 c4 = cp4[k]; float4 zz = z4[k];
                float dx = c4.x - zz.x, dy = c4.y - zz.y;
                float dz = c4.z - zz.z, dw = c4.w - zz.w;
                float4 q;
                q.x = zz.x + dx; q.y = zz.y + dy;
                q.z = zz.z + dz; q.w = zz.w + dw;
                qp[k] = q;
                dd += (double)dx * dx + (double)dy * dy
                    + (double)dz * dz + (double)dw * dw;
            }
            best_s[tl] = best;
            da += dd;
        }
#pragma unroll
        for (int off = 32; off > 0; off >>= 1)
            da += __shfl_down(da, off, 64);
        if (lane == 0) dredA[wid] = da;
    }

    // ---- fix-B: full scan, token-per-lane, codes wave-partitioned ----
    // zB transposed+swizzled in sbuf: slot(k,tok) = k*64 + (tok ^ (k&31)).
    // Two-pass f32 prescreen (identical DAG) gates exact-f64 refine to
    // ~1-3 codes/token; window 5e-4 >> 2e-5 cross-formula deviation.
    {
        float* zB = (float*)sbuf;                       // [64][64] f32 swizzled
        unsigned* dmb = (unsigned*)(sbuf + 16384);      // 64 u32 prescreen min
        u64* keyB = (u64*)(sbuf + 16640);               // 64 u64 packed keys
        double db = 0.0;
        for (int c0 = 0; c0 < nB; c0 += 64) {
            const int nc = min(64, nB - c0);
            if (tid < 64) { dmb[tid] = 0x7f800000u; keyB[tid] = ~0ull; }
            // stage: tok-major threads (coalesced-ish gather, conflict-free LDS)
            {
                const int tok = tid & 63, f4 = tid >> 6;   // 16 f4 per token
                if (tok < nc) {
                    const int tl = listB[c0 + tok];
                    const float4 v = ((const float4*)z)[
                        (size_t)(blk_tok0 + tl) * 16 + f4];
                    const int k0 = f4 * 4;
                    zB[(k0 + 0) * 64 + (tok ^ ((k0 + 0) & 31))] = v.x;
                    zB[(k0 + 1) * 64 + (tok ^ ((k0 + 1) & 31))] = v.y;
                    zB[(k0 + 2) * 64 + (tok ^ ((k0 + 2) & 31))] = v.z;
                    zB[(k0 + 3) * 64 + (tok ^ ((k0 + 3) & 31))] = v.w;
                }
            }
            __syncthreads();
            const bool act = lane < nc;
            // z into registers (conflict-free LDS reads)
            float zf[64];
#pragma unroll
            for (int k = 0; k < 64; ++k)
                zf[k] = zB[k * 64 + (lane ^ (k & 31))];
            // numpy-pairwise z2 (exact copies, validated op order)
            float r8[8];
#pragma unroll
            for (int j = 0; j < 8; ++j) r8[j] = __fmul_rn(zf[j], zf[j]);
#pragma unroll
            for (int i = 8; i < 64; i += 8)
#pragma unroll
                for (int j = 0; j < 8; ++j)
                    r8[j] = __fadd_rn(r8[j], __fmul_rn(zf[i + j], zf[i + j]));
            const float z2 = __fadd_rn(
                __fadd_rn(__fadd_rn(r8[0], r8[1]), __fadd_rn(r8[2], r8[3])),
                __fadd_rn(__fadd_rn(r8[4], r8[5]), __fadd_rn(r8[6], r8[7])));

            auto dfun = [&](int e) -> float {   // wave-uniform cb row
                const float4* cp4 = (const float4*)(cb + (size_t)e * E_DIM);
                float a0 = 0.f, a1 = 0.f, a2 = 0.f, a3 = 0.f;
#pragma unroll
                for (int k4 = 0; k4 < 16; ++k4) {
                    float4 c4 = cp4[k4];
                    a0 = fmaf(zf[k4 * 4],     c4.x, a0);
                    a1 = fmaf(zf[k4 * 4 + 1], c4.y, a1);
                    a2 = fmaf(zf[k4 * 4 + 2], c4.z, a2);
                    a3 = fmaf(zf[k4 * 4 + 3], c4.w, a3);
                }
                union { unsigned short u; _Float16 h; } cv;
                cv.u = c2s[e];
                float c2a = (float)cv.h * (-1.0f / 512.0f);
                return z2 + c2a - 2.0f * ((a0 + a1) + (a2 + a3));
            };

            // pass 1: per-lane min over this wave's 64 codes
            float dminw = 1e30f;
            for (int i = 0; i < 64; ++i)
                dminw = fminf(dminw, dfun(wid * 64 + i));
            if (act) atomicMin(&dmb[lane], __float_as_uint(dminw));
            __syncthreads();
            // pass 2: refine codes within window of the global min
            const float thr = __uint_as_float(dmb[lane & 63]) + 5e-4f;
            for (int i = 0; i < 64; ++i) {
                const int e = wid * 64 + i;
                const float d = dfun(e);        // identical DAG -> identical d
                if (act && d <= thr) {
                    const float* cp = cb + (size_t)e * E_DIM;
                    double cs = 0.0, mm = 0.0;
#pragma unroll
                    for (int k = 0; k < E_DIM; ++k) {
                        double cc = (double)cp[k];
                        cs = fma(cc, cc, cs);
                        mm = fma((double)zf[k], cc, mm);
                    }
                    float dd = __fsub_rn(__fadd_rn(z2, (float)cs),
                                         __fmul_rn(2.0f, (float)mm));
                    u64 key = ((u64)__float_as_uint(dd) << 32) | (unsigned)e;
                    atomicMin(&keyB[lane], key);
                }
            }
            __syncthreads();
            // apply: wave-cooperative row writes
            for (int tok = wid; tok < nc; tok += 16) {
                const int best = (int)(keyB[tok] & 0xffffffffull);
                const int tl = listB[c0 + tok];
                const int n  = blk_tok0 + tl;
                float cv2 = cb[(size_t)best * E_DIM + lane];
                float zi  = zB[lane * 64 + (tok ^ (lane & 31))];
                float diff = cv2 - zi;
                out[ZQ_OFF + (size_t)n * E_DIM + lane] = zi + diff;
                double d2 = (double)diff * (double)diff;
#pragma unroll
                for (int off = 32; off > 0; off >>= 1)
                    d2 += __shfl_down(d2, off, 64);
                if (lane == 0) { db += d2; best_s[tl] = best; }
            }
            __syncthreads();   // zB/dmb/keyB reusable next chunk
        }
        if (lane == 0) dredB[wid] = db;
    }

    __syncthreads();

    // unified coalesced idx write + per-block sum_sq slot (non-atomic)
    if (tid < 512)
        out[IDX_OFF + blk_tok0 + tid] = (float)best_s[tid];
    if (tid == 0) {
        double s = 0.0;
#pragma unroll
        for (int i = 0; i < 16; ++i) s += wred[i] + dredA[i] + dredB[i];
        slots[blockIdx.x] = s;
    }
}

// Single-block finalize: histogram straight from the idx array, entropy,
// mse from the 256 per-block slots. (Validated R5.)
__global__ __launch_bounds__(1024) void finalize2(
    const double* __restrict__ slots, float* __restrict__ out) {
    __shared__ int hist[N_E];
    __shared__ double red[1024];
    const int tid = threadIdx.x;
    hist[tid] = 0;
    __syncthreads();
    const float4* idx4 = (const float4*)(out + IDX_OFF);
    for (int i = tid; i < N_TOK / 4; i += 1024) {
        float4 v = idx4[i];
        atomicAdd(&hist[(int)v.x], 1);
        atomicAdd(&hist[(int)v.y], 1);
        atomicAdd(&hist[(int)v.z], 1);
        atomicAdd(&hist[(int)v.w], 1);
    }
    __syncthreads();
    double em = (double)hist[tid] / (double)N_TOK;
    red[tid] = -em * log(em + 1e-10);
    __syncthreads();
    for (int s = 512; s > 0; s >>= 1) {
        if (tid < s) red[tid] += red[tid + s];
        __syncthreads();
    }
    if (tid == 0) {
        double usage = red[0];
        double ss = 0.0;
        for (int i = 0; i < 256; ++i) ss += slots[i];
        double mse = ss / (double)((size_t)N_TOK * E_DIM);
        out[LOSS_OFF] = (float)((1.0 + BETA) * mse + 0.01 * usage);
        out[PERP_OFF] = (float)exp(usage);
    }
}

extern "C" void kernel_launch(void* const* d_in, const int* in_sizes, int n_in,
                              void* d_out, int out_size, void* d_ws, size_t ws_size,
                              hipStream_t stream) {
    const float* z  = (const float*)d_in[0];
    const float* cb = (const float*)d_in[1];
    float* out = (float*)d_out;
    double* slots = (double*)d_ws;   // 256 doubles

    // u''-space margin 0.071 validated rounds 1-5 (absmax 0 throughout).
    vq_all<<<256, 1024, 0, stream>>>(z, cb, slots, 0.071f, out);
    finalize2<<<1, 1024, 0, stream>>>(slots, out);
}

// Round 8
// 248.252 us; speedup vs baseline: 3.4613x; 3.4613x over previous
//
#include <hip/hip_runtime.h>
#include <math.h>

#define N_TOK 131072
#define N_E   1024
#define E_DIM 64
#define BETA  0.4

// d_out layout (float32, concatenated in return order):
#define ZQ_OFF   0
#define LOSS_OFF 8388608
#define IDX_OFF  8388609
#define PERP_OFF 8519681

// d_ws layout (105 KB of the >=532 KB proven workspace). Every region is
// either unconditionally written before read (slots, c2, wlBcnt) or
// initialized inside vq_all before its consumer kernel runs (keysB).
#define WS_SLOTS 0        // 256 doubles: per-block sum_sq partials
#define WS_C2    2048     // 1024 f32: RN32(exact ||c_e||^2), by vq_all block 0
#define WS_BCNT  6144     // 256 ints: per-block typ2 counts (always written)
#define WS_WLB   7168     // 8192 ints: per-block 32-slot typ2 token regions
#define WS_KEYSB 39936    // 8192 u64: packed (d_bits<<32)|e per slot

typedef _Float16 f16x8 __attribute__((ext_vector_type(8)));
typedef float f32x4  __attribute__((ext_vector_type(4)));
typedef unsigned long long u64;

__device__ __forceinline__ unsigned med3u(unsigned a, unsigned b, unsigned c) {
    unsigned d;
    asm("v_med3_u32 %0, %1, %2, %3" : "=v"(d) : "v"(a), "v"(b), "v"(c));
    return d;
}

// Cold path (per-block typ2 overflow only, P~1e-12). Exact semantics,
// streaming (no big arrays -> no spill). c2 recomputed inline in f64
// (== RN32 exact, proven equivalent R6 fix-A).
__device__ __attribute__((noinline)) int exact_best_serial2(
    const float* __restrict__ z, const float* __restrict__ cb, int n) {
    const float* zr = z + (size_t)n * E_DIM;
    float r8[8];
#pragma unroll
    for (int j = 0; j < 8; ++j) r8[j] = __fmul_rn(zr[j], zr[j]);
#pragma unroll 1
    for (int i = 8; i < 64; i += 8)
#pragma unroll
        for (int j = 0; j < 8; ++j)
            r8[j] = __fadd_rn(r8[j], __fmul_rn(zr[i + j], zr[i + j]));
    float z2 = __fadd_rn(__fadd_rn(__fadd_rn(r8[0], r8[1]), __fadd_rn(r8[2], r8[3])),
                         __fadd_rn(__fadd_rn(r8[4], r8[5]), __fadd_rn(r8[6], r8[7])));
    u64 bestkey = ~0ull;
#pragma unroll 1
    for (int e = 0; e < N_E; ++e) {
        const float* cp = cb + (size_t)e * E_DIM;
        double cs = 0.0, mm = 0.0;
#pragma unroll 1
        for (int i = 0; i < E_DIM; ++i) {
            double cc = (double)cp[i];
            cs = fma(cc, cc, cs);
            mm = fma((double)zr[i], cc, mm);
        }
        float d = __fsub_rn(__fadd_rn(z2, (float)cs), __fmul_rn(2.0f, (float)mm));
        u64 key = ((u64)__float_as_uint(d) << 32) | (unsigned)e;
        if (key < bestkey) bestkey = key;
    }
    return (int)(bestkey & 0xffffffffu);
}

// Dispatch 1: 256 blocks x 1024 threads (1 block/CU). Coalesced frag ->
// LDS fp16 codebook, c2s from frags, fp16 MFMA screen, top-3 route
// (settled / 2-cand in-block / full-scan -> per-block global wlB region),
// settled epilogue, STREAMING in-block fix-A (no per-thread arrays ->
// no scratch spill; R6's 64-float arrays under the 64-VGPR budget were
// the 813us regression). Block 0 also writes exact f32 c2[] for the scan.
__global__ __launch_bounds__(1024, 4) void vq_all(
    const float* __restrict__ z, const float* __restrict__ cb,
    double* __restrict__ slots, float* __restrict__ c2g,
    int* __restrict__ wlBcnt, int* __restrict__ wlB,
    u64* __restrict__ keysB, float margin_u, float* __restrict__ out) {

    __shared__ __align__(16) unsigned char sbuf[131072];
    __shared__ __align__(8)  unsigned short c2s[N_E];
    __shared__ int   best_s[512];
    __shared__ unsigned char flag_s[512];
    __shared__ unsigned listA[512];        // (tl<<20)|(e1<<10)|e2
    __shared__ int cntA, cntB;
    __shared__ double wred[16], dredA[16];

    const int tid  = threadIdx.x;
    const int lane = tid & 63;
    const int wid  = tid >> 6;
    const int col  = lane & 15;
    const int quad = lane >> 4;
    const int blk_tok0 = blockIdx.x * 512;
    const int wave_tok0 = blk_tok0 + wid * 32;

    if (tid == 0) { cntA = 0; cntB = 0; }
    // init this block's keysB slots (consumed only by the NEXT kernel)
    if (tid < 32) keysB[blockIdx.x * 32 + tid] = ~0ull;

    // z fragment loads first (HBM latency overlaps frag phase)
    float4 zl[2][4];
#pragma unroll
    for (int m = 0; m < 2; ++m) {
        const float* zr = z + (size_t)(wave_tok0 + m * 16 + col) * E_DIM + quad * 8;
#pragma unroll
        for (int kc = 0; kc < 2; ++kc) {
            zl[m][kc * 2]     = *(const float4*)(zr + kc * 32);
            zl[m][kc * 2 + 1] = *(const float4*)(zr + kc * 32 + 4);
        }
    }

    // frag: COALESCED cb read, scattered 8B LDS write (R6-validated map).
    {
        const float4* cb4 = (const float4*)cb;
#pragma unroll
        for (int r = 0; r < 16; ++r) {
            const int ft = r * 1024 + tid;
            const float4 v = cb4[ft];
            const int code = ft >> 4;
            const int k0   = (ft & 15) * 4;
            const int cc = ((code >> 4) << 1) | (k0 >> 5);
            const int l  = (((k0 >> 3) & 3) << 4) | (code & 15);
            const int dst = (cc << 9) | (l << 3) | (k0 & 7);
            union { _Float16 h[4]; uint2 u; } pk;
            pk.h[0] = (_Float16)(v.x * 1024.0f);
            pk.h[1] = (_Float16)(v.y * 1024.0f);
            pk.h[2] = (_Float16)(v.z * 1024.0f);
            pk.h[3] = (_Float16)(v.w * 1024.0f);
            *(uint2*)(sbuf + dst * 2) = pk.u;
        }
    }

    // block 0: exact f32 c2 for the scan kernel (validated frag_kernel order)
    if (blockIdx.x == 0) {
        const float* p = cb + (size_t)tid * E_DIM;
        double s = 0.0;
#pragma unroll
        for (int k = 0; k < E_DIM; ++k) {
            double c = (double)p[k];
            s = fma(c, c, s);
        }
        c2g[tid] = (float)s;
    }
    __syncthreads();   // frags visible

    // c2s from LDS frags (R6-validated; fp16 precision, error << margin)
    {
        const int code = tid;
        const int cc0 = (code >> 4) << 1;
        const int c15 = code & 15;
        float s = 0.f;
#pragma unroll
        for (int half = 0; half < 2; ++half)
#pragma unroll
            for (int lv = 0; lv < 4; ++lv) {
                const int off = (((cc0 + half) << 9) |
                                 (((lv << 4) | c15) << 3)) * 2;
                union { uint4 u; _Float16 h[8]; } b;
                b.u = *(const uint4*)(sbuf + off);
#pragma unroll
                for (int j = 0; j < 8; ++j) {
                    float f = (float)b.h[j];
                    s = fmaf(f, f, s);
                }
            }
        union { _Float16 h; unsigned short u; } q;
        q.h = (_Float16)(s * (-1.0f / 2048.0f));
        c2s[tid] = q.u;
    }

    // A fragments
    f16x8 Ah[2][2];
#pragma unroll
    for (int m = 0; m < 2; ++m)
#pragma unroll
        for (int kc = 0; kc < 2; ++kc) {
            float4 u0 = zl[m][kc * 2], u1 = zl[m][kc * 2 + 1];
            f16x8 a;
            a[0] = (_Float16)u0.x; a[1] = (_Float16)u0.y;
            a[2] = (_Float16)u0.z; a[3] = (_Float16)u0.w;
            a[4] = (_Float16)u1.x; a[5] = (_Float16)u1.y;
            a[6] = (_Float16)u1.z; a[7] = (_Float16)u1.w;
            Ah[m][kc] = a;
        }

    // top-3 packed-key MAX tracker
    unsigned k1[2][4], k2[2][4], k3[2][4];
#pragma unroll
    for (int m = 0; m < 2; ++m)
#pragma unroll
        for (int r = 0; r < 4; ++r) { k1[m][r] = 0u; k2[m][r] = 0u; k3[m][r] = 0u; }

    __syncthreads();   // c2s complete

    // sweep: u'' = 1024*dot - 512*c2 + 64 > 0; key = (bits&~63)|(63-cl)
#pragma unroll 4
    for (int cl = 0; cl < 64; ++cl) {
        const unsigned char* bp = sbuf + cl * 2048 + lane * 16;
        union { uint4 u; f16x8 v; } b0, b1;
        b0.u = *(const uint4*)(bp);
        b1.u = *(const uint4*)(bp + 1024);
        union { unsigned short us; _Float16 h; } cv;
        cv.us = c2s[cl * 16 + col];
        const float ch = 64.0f + (float)cv.h;
        const f32x4 cinit = {ch, ch, ch, ch};
        const unsigned ctag = (unsigned)(63 - cl);
#pragma unroll
        for (int m = 0; m < 2; ++m) {
            f32x4 acc = __builtin_amdgcn_mfma_f32_16x16x32_f16(
                Ah[m][0], b0.v, cinit, 0, 0, 0);
            acc = __builtin_amdgcn_mfma_f32_16x16x32_f16(
                Ah[m][1], b1.v, acc, 0, 0, 0);
#pragma unroll
            for (int r = 0; r < 4; ++r) {
                unsigned key = (__float_as_uint(acc[r]) & 0xFFFFFFC0u) | ctag;
                unsigned t1 = min(k1[m][r], key);
                k3[m][r] = med3u(k2[m][r], k3[m][r], t1);
                k2[m][r] = med3u(k1[m][r], k2[m][r], key);
                k1[m][r] = max(k1[m][r], key);
            }
        }
    }

    // merge + route (validated R4-R6); typ2 -> per-block global wlB region
#pragma unroll 1
    for (int m = 0; m < 2; ++m) {
#pragma unroll 1
        for (int r = 0; r < 4; ++r) {
            const unsigned l1 = k1[m][r], l2 = k2[m][r], l3 = k3[m][r];
            unsigned g1 = l1, g2 = l2, g3 = l3;
#pragma unroll
            for (int d = 1; d < 16; d <<= 1) {
                unsigned p1 = __shfl_xor(g1, d, 64);
                unsigned p2 = __shfl_xor(g2, d, 64);
                unsigned p3 = __shfl_xor(g3, d, 64);
                unsigned t1 = min(g1, p1);
                g3 = med3u(g2, g3, t1);
                g2 = med3u(g1, g2, p1);
                g1 = max(g1, p1);
                g3 = med3u(g2, g3, p2);
                g2 = max(g2, p2);
                g3 = med3u(g2, g3, p3);
            }
            u64 bal1 = __ballot((l1 == g1) || (l2 == g1) || (l3 == g1));
            u64 bal2 = __ballot((l1 == g2) || (l2 == g2) || (l3 == g2));
            if (col == 0) {
                const int tl = wid * 32 + m * 16 + quad * 4 + r;
                const int n  = blk_tok0 + tl;
                unsigned m1 = (unsigned)((bal1 >> (quad * 16)) & 0xFFFFu);
                int c1 = __ffs(m1) - 1;
                int bbest = (63 - (int)(g1 & 63u)) * 16 + c1;
                float v1 = __uint_as_float(g1 & 0xFFFFFFC0u);
                float v2 = __uint_as_float(g2 & 0xFFFFFFC0u);
                float v3 = __uint_as_float(g3 & 0xFFFFFFC0u);
                int typ = 0, bsec = 0;
                if (v1 - v2 < margin_u) {
                    if (v1 - v3 < margin_u) typ = 2;
                    else {
                        unsigned m2 = (unsigned)((bal2 >> (quad * 16)) & 0xFFFFu);
                        if (g2 == g1) m2 &= ~(1u << c1);
                        if (__popc(m2) == 1) {
                            bsec = (63 - (int)(g2 & 63u)) * 16 + (__ffs(m2) - 1);
                            typ = 1;
                        } else typ = 2;
                    }
                }
                if (typ == 1) {
                    int pos = atomicAdd(&cntA, 1);
                    listA[pos] = ((unsigned)tl << 20) |
                                 ((unsigned)bbest << 10) | (unsigned)bsec;
                } else if (typ == 2) {
                    int pos = atomicAdd(&cntB, 1);
                    if (pos < 32) wlB[blockIdx.x * 32 + pos] = n;
                    else { bbest = exact_best_serial2(z, cb, n); typ = 0; }
                }
                best_s[tl] = bbest;
                flag_s[tl] = typ ? 1 : 0;
            }
        }
    }

    // settled epilogue: coalesced z_q / loss partials (own-wave tokens only)
    {
        const int sub = lane & 15, grp = lane >> 4;
        double dl = 0.0;
        const float4* zrow = (const float4*)z;
        const float4* crow = (const float4*)cb;
        float4* qrow = (float4*)(out + ZQ_OFF);
#pragma unroll
        for (int p = 0; p < 8; ++p) {
            int tl = wid * 32 + p * 4 + grp;
            if (!flag_s[tl]) {
                int n = blk_tok0 + tl;
                float4 z4 = zrow[(size_t)n * 16 + sub];
                float4 c4 = crow[(size_t)best_s[tl] * 16 + sub];
                float dx = c4.x - z4.x, dy = c4.y - z4.y;
                float dz = c4.z - z4.z, dw = c4.w - z4.w;
                float4 q;
                q.x = z4.x + dx; q.y = z4.y + dy;
                q.z = z4.z + dz; q.w = z4.w + dw;
                qrow[(size_t)n * 16 + sub] = q;
                dl += (double)dx * dx + (double)dy * dy
                    + (double)dz * dz + (double)dw * dw;
            }
        }
#pragma unroll
        for (int off = 32; off > 0; off >>= 1)
            dl += __shfl_down(dl, off, 64);
        if (lane == 0) wred[wid] = dl;
    }

    __syncthreads();   // lists final
    const int nA = cntA;
    if (tid == 0) wlBcnt[blockIdx.x] = min(cntB, 32);

    // ---- fix-A: 2-candidate exact, thread-per-entry, FULLY STREAMING ----
    {
        double da = 0.0;
        for (int t = tid; t < nA; t += 1024) {
            const unsigned ent = listA[t];
            const int tl = (int)(ent >> 20);
            const int e1 = (int)((ent >> 10) & 1023u);
            const int e2 = (int)(ent & 1023u);
            const int n  = blk_tok0 + tl;
            const float* zr = z + (size_t)n * E_DIM;
            // z2: numpy-pairwise, streaming scalar reads (L1-hot)
            float r8[8];
#pragma unroll
            for (int j = 0; j < 8; ++j) r8[j] = __fmul_rn(zr[j], zr[j]);
#pragma unroll
            for (int i = 8; i < 64; i += 8)
#pragma unroll
                for (int j = 0; j < 8; ++j)
                    r8[j] = __fadd_rn(r8[j], __fmul_rn(zr[i + j], zr[i + j]));
            float z2 = __fadd_rn(
                __fadd_rn(__fadd_rn(r8[0], r8[1]), __fadd_rn(r8[2], r8[3])),
                __fadd_rn(__fadd_rn(r8[4], r8[5]), __fadd_rn(r8[6], r8[7])));
            u64 bk = ~0ull;
#pragma unroll
            for (int c = 0; c < 2; ++c) {
                const int e = c ? e2 : e1;
                const float* cp = cb + (size_t)e * E_DIM;
                double cs = 0.0, mm = 0.0;
#pragma unroll
                for (int k = 0; k < E_DIM; ++k) {
                    double cc = (double)cp[k];
                    cs = fma(cc, cc, cs);
                    mm = fma((double)zr[k], cc, mm);
                }
                float d = __fsub_rn(__fadd_rn(z2, (float)cs),
                                    __fmul_rn(2.0f, (float)mm));
                u64 key = ((u64)__float_as_uint(d) << 32) | (unsigned)e;
                if (key < bk) bk = key;
            }
            const int best = (int)(bk & 0xffffffffull);
            // apply: streaming float4 (no arrays)
            const float4* cp4 = (const float4*)(cb + (size_t)best * E_DIM);
            const float4* zp4 = (const float4*)zr;
            float4* qp = (float4*)(out + ZQ_OFF + (size_t)n * E_DIM);
            double dd = 0.0;
#pragma unroll
            for (int k = 0; k < 16; ++k) {
                float4 c4 = cp4[k]; float4 zz = zp4[k];
                float dx = c4.x - zz.x, dy = c4.y - zz.y;
                float dz = c4.z - zz.z, dw = c4.w - zz.w;
                float4 q;
                q.x = zz.x + dx; q.y = zz.y + dy;
                q.z = zz.z + dz; q.w = zz.w + dw;
                qp[k] = q;
                dd += (double)dx * dx + (double)dy * dy
                    + (double)dz * dz + (double)dw * dw;
            }
            best_s[tl] = best;
            da += dd;
        }
#pragma unroll
        for (int off = 32; off > 0; off >>= 1)
            da += __shfl_down(da, off, 64);
        if (lane == 0) dredA[wid] = da;
    }

    __syncthreads();

    // coalesced idx write (typ2 slots are placeholders, fixed by finalize3)
    if (tid < 512)
        out[IDX_OFF + blk_tok0 + tid] = (float)best_s[tid];
    if (tid == 0) {
        double s = 0.0;
#pragma unroll
        for (int i = 0; i < 16; ++i) s += wred[i] + dredA[i];
        slots[blockIdx.x] = s;
    }
}

// Dispatch 2: full scan for typ2 slots — R4's proven kernel (small blocks so
// zf[64] stays in registers), slot-indexed over per-block regions.
// 128 groups x 32 code-slices = 4096 blocks x 64 threads.
__global__ __launch_bounds__(64) void fixup_scan(
    const float* __restrict__ z, const float* __restrict__ cb,
    const float* __restrict__ c2, const int* __restrict__ wlB,
    const int* __restrict__ wlBcnt, u64* __restrict__ keysB) {

    const int g = blockIdx.x >> 5;
    const int s = blockIdx.x & 31;
    const int cnt0 = wlBcnt[g * 2], cnt1 = wlBcnt[g * 2 + 1];
    if (cnt0 == 0 && cnt1 == 0) return;
    const int lane = threadIdx.x;
    const int w = g * 64 + lane;
    const bool valid = (lane & 31) < (lane < 32 ? cnt0 : cnt1);
    int n = 0;
    if (valid) n = wlB[w];

    float zf[E_DIM];
    const float4* zp = (const float4*)(z + (size_t)n * E_DIM);
#pragma unroll
    for (int k = 0; k < 16; ++k) {
        float4 v = zp[k];
        zf[4 * k] = v.x; zf[4 * k + 1] = v.y;
        zf[4 * k + 2] = v.z; zf[4 * k + 3] = v.w;
    }
    float r8[8];
#pragma unroll
    for (int j = 0; j < 8; ++j) r8[j] = __fmul_rn(zf[j], zf[j]);
#pragma unroll
    for (int i = 8; i < 64; i += 8)
#pragma unroll
        for (int j = 0; j < 8; ++j)
            r8[j] = __fadd_rn(r8[j], __fmul_rn(zf[i + j], zf[i + j]));
    const float z2 = __fadd_rn(
        __fadd_rn(__fadd_rn(r8[0], r8[1]), __fadd_rn(r8[2], r8[3])),
        __fadd_rn(__fadd_rn(r8[4], r8[5]), __fadd_rn(r8[6], r8[7])));

    const int e0 = s * 32;
    float d32[32];
    float dmin = 1e30f;
#pragma unroll 4
    for (int i = 0; i < 32; ++i) {
        const float* cp = cb + (size_t)(e0 + i) * E_DIM;   // wave-uniform row
        float a0 = 0.f, a1 = 0.f, a2 = 0.f, a3 = 0.f;
#pragma unroll
        for (int k = 0; k < 64; k += 4) {
            a0 = fmaf(zf[k],     cp[k],     a0);
            a1 = fmaf(zf[k + 1], cp[k + 1], a1);
            a2 = fmaf(zf[k + 2], cp[k + 2], a2);
            a3 = fmaf(zf[k + 3], cp[k + 3], a3);
        }
        float d = z2 + c2[e0 + i] - 2.0f * ((a0 + a1) + (a2 + a3));
        d32[i] = d;
        dmin = fminf(dmin, d);
    }
    u64 best = ~0ull;
    const float thr = dmin + 4e-3f;   // R4-validated window
    for (int it = 0; it < 32; ++it) {
        float dm = d32[0]; int am = 0;
#pragma unroll
        for (int i = 1; i < 32; ++i) {
            bool t = d32[i] < dm;
            dm = t ? d32[i] : dm;
            am = t ? i : am;
        }
        bool need = dm <= thr;
        if (!__any(need)) break;
        if (need) {
            int e = e0 + am;
            const float* cp = cb + (size_t)e * E_DIM;
            double mm = 0.0;
#pragma unroll
            for (int i = 0; i < E_DIM; ++i)
                mm = fma((double)zf[i], (double)cp[i], mm);
            float d = __fsub_rn(__fadd_rn(z2, c2[e]),
                                __fmul_rn(2.0f, (float)mm));
            u64 key = ((u64)__float_as_uint(d) << 32) | (unsigned)e;
            if (key < best) best = key;
#pragma unroll
            for (int i = 0; i < 32; ++i)     // static-indexed invalidate
                if (i == am) d32[i] = 1e30f;
        }
    }
    if (valid && best != ~0ull) atomicMin(&keysB[w], best);
}

// Dispatch 3: apply typ2 results (streaming), histogram from the idx array,
// entropy + mse. Single block x 1024.
__global__ __launch_bounds__(1024) void finalize3(
    const float* __restrict__ z, const float* __restrict__ cb,
    const int* __restrict__ wlB, const int* __restrict__ wlBcnt,
    const u64* __restrict__ keysB, const double* __restrict__ slots,
    float* __restrict__ out) {

    __shared__ int hist[N_E];
    __shared__ double red[1024];
    __shared__ double ssq_s;
    const int tid = threadIdx.x;
    hist[tid] = 0;

    // apply typ2 tokens (streaming, no arrays)
    double myss = 0.0;
    for (int w = tid; w < 8192; w += 1024) {
        if ((w & 31) < wlBcnt[w >> 5]) {
            const int n = wlB[w];
            const int best = (int)(keysB[w] & 0xffffffffull);
            const float4* cp4 = (const float4*)(cb + (size_t)best * E_DIM);
            const float4* zp4 = (const float4*)(z + (size_t)n * E_DIM);
            float4* qp = (float4*)(out + ZQ_OFF + (size_t)n * E_DIM);
            double dd = 0.0;
#pragma unroll
            for (int k = 0; k < 16; ++k) {
                float4 c4 = cp4[k]; float4 zz = zp4[k];
                float dx = c4.x - zz.x, dy = c4.y - zz.y;
                float dz = c4.z - zz.z, dw = c4.w - zz.w;
                float4 q;
                q.x = zz.x + dx; q.y = zz.y + dy;
                q.z = zz.z + dz; q.w = zz.w + dw;
                qp[k] = q;
                dd += (double)dx * dx + (double)dy * dy
                    + (double)dz * dz + (double)dw * dw;
            }
            out[IDX_OFF + n] = (float)best;
            myss += dd;
        }
    }

    // sum_sq reduce (apply partials + the 256 vq_all slots, in parallel)
    red[tid] = myss + (tid < 256 ? slots[tid] : 0.0);
    __syncthreads();
    for (int s = 512; s > 0; s >>= 1) {
        if (tid < s) red[tid] += red[tid + s];
        __syncthreads();
    }
    if (tid == 0) ssq_s = red[0];
    __syncthreads();   // also drains apply writes before hist re-reads idx

    // histogram from idx (vq_all writes visible across kernel boundary;
    // own apply writes visible after the sync above; no stale L1 copies)
    const float4* idx4 = (const float4*)(out + IDX_OFF);
    for (int i = tid; i < N_TOK / 4; i += 1024) {
        float4 v = idx4[i];
        atomicAdd(&hist[(int)v.x], 1);
        atomicAdd(&hist[(int)v.y], 1);
        atomicAdd(&hist[(int)v.z], 1);
        atomicAdd(&hist[(int)v.w], 1);
    }
    __syncthreads();
    double em = (double)hist[tid] / (double)N_TOK;
    red[tid] = -em * log(em + 1e-10);
    __syncthreads();
    for (int s = 512; s > 0; s >>= 1) {
        if (tid < s) red[tid] += red[tid + s];
        __syncthreads();
    }
    if (tid == 0) {
        double usage = red[0];
        double mse = ssq_s / (double)((size_t)N_TOK * E_DIM);
        out[LOSS_OFF] = (float)((1.0 + BETA) * mse + 0.01 * usage);
        out[PERP_OFF] = (float)exp(usage);
    }
}

extern "C" void kernel_launch(void* const* d_in, const int* in_sizes, int n_in,
                              void* d_out, int out_size, void* d_ws, size_t ws_size,
                              hipStream_t stream) {
    const float* z  = (const float*)d_in[0];
    const float* cb = (const float*)d_in[1];
    float* out = (float*)d_out;

    double* slots  = (double*)((char*)d_ws + WS_SLOTS);
    float*  c2g    = (float*)((char*)d_ws + WS_C2);
    int*    wlBcnt = (int*)((char*)d_ws + WS_BCNT);
    int*    wlB    = (int*)((char*)d_ws + WS_WLB);
    u64*    keysB  = (u64*)((char*)d_ws + WS_KEYSB);

    // u''-space margin 0.071 validated rounds 1-6 (absmax 0 throughout).
    vq_all<<<256, 1024, 0, stream>>>(z, cb, slots, c2g, wlBcnt, wlB, keysB,
                                     0.071f, out);
    fixup_scan<<<4096, 64, 0, stream>>>(z, cb, c2g, wlB, wlBcnt, keysB);
    finalize3<<<1, 1024, 0, stream>>>(z, cb, wlB, wlBcnt, keysB, slots, out);
}

// Round 9
// 192.165 us; speedup vs baseline: 4.4716x; 1.2919x over previous
//
#include <hip/hip_runtime.h>
#include <math.h>

#define N_TOK 131072
#define N_E   1024
#define E_DIM 64
#define BETA  0.4

// d_out layout (float32, concatenated in return order):
#define ZQ_OFF   0
#define LOSS_OFF 8388608
#define IDX_OFF  8388609
#define PERP_OFF 8519681

// d_ws layout (106 KB of the >=532 KB proven workspace).
#define WS_SLOTS 0        // 256 doubles: per-block sum_sq partials
#define WS_C2    2048     // 1024 f32: RN32(exact ||c_e||^2), by vq_all block 0
#define WS_CNT   6144     // 1024 i32 global counts (memset to 0)
#define WS_WLC   10240    // i32 global typ2 count (memset with counts)
#define WS_WLB   10256    // 8192 ints: COMPACT typ2 token list
#define WS_KEYSB 43024    // 8192 u64: packed (d_bits<<32)|e per compact slot
#define WLCAP    8192

typedef _Float16 f16x8 __attribute__((ext_vector_type(8)));
typedef float f32x4  __attribute__((ext_vector_type(4)));
typedef unsigned long long u64;

__device__ __forceinline__ unsigned med3u(unsigned a, unsigned b, unsigned c) {
    unsigned d;
    asm("v_med3_u32 %0, %1, %2, %3" : "=v"(d) : "v"(a), "v"(b), "v"(c));
    return d;
}

// Cold path (global typ2 overflow only, P~0 at cap 8192 vs ~2k expected).
__device__ __attribute__((noinline)) int exact_best_serial2(
    const float* __restrict__ z, const float* __restrict__ cb, int n) {
    const float* zr = z + (size_t)n * E_DIM;
    float r8[8];
#pragma unroll
    for (int j = 0; j < 8; ++j) r8[j] = __fmul_rn(zr[j], zr[j]);
#pragma unroll 1
    for (int i = 8; i < 64; i += 8)
#pragma unroll
        for (int j = 0; j < 8; ++j)
            r8[j] = __fadd_rn(r8[j], __fmul_rn(zr[i + j], zr[i + j]));
    float z2 = __fadd_rn(__fadd_rn(__fadd_rn(r8[0], r8[1]), __fadd_rn(r8[2], r8[3])),
                         __fadd_rn(__fadd_rn(r8[4], r8[5]), __fadd_rn(r8[6], r8[7])));
    u64 bestkey = ~0ull;
#pragma unroll 1
    for (int e = 0; e < N_E; ++e) {
        const float* cp = cb + (size_t)e * E_DIM;
        double cs = 0.0, mm = 0.0;
#pragma unroll 1
        for (int i = 0; i < E_DIM; ++i) {
            double cc = (double)cp[i];
            cs = fma(cc, cc, cs);
            mm = fma((double)zr[i], cc, mm);
        }
        float d = __fsub_rn(__fadd_rn(z2, (float)cs), __fmul_rn(2.0f, (float)mm));
        u64 key = ((u64)__float_as_uint(d) << 32) | (unsigned)e;
        if (key < bestkey) bestkey = key;
    }
    return (int)(bestkey & 0xffffffffu);
}

// Dispatch 2 of 4: 256 blocks x 1024 threads. R8-validated core (frag, c2s,
// MFMA screen, top-3 route, settled epilogue, streaming fix-A) + NEW:
// (a) per-block LDS histogram -> global counts (finalize no longer re-reads
//     the 0.5MB idx array single-block — that was ~70us);
// (b) compact global typ2 worklist (scan blocks early-exit like R4 — the
//     per-block-region scan made all 4096 scan blocks work, 4x R4).
__global__ __launch_bounds__(1024, 4) void vq_all(
    const float* __restrict__ z, const float* __restrict__ cb,
    double* __restrict__ slots, float* __restrict__ c2g,
    int* __restrict__ counts, int* __restrict__ wlCnt,
    int* __restrict__ wlB, u64* __restrict__ keysB,
    float margin_u, float* __restrict__ out) {

    __shared__ __align__(16) unsigned char sbuf[131072];
    __shared__ __align__(8)  unsigned short c2s[N_E];
    __shared__ int   best_s[512];
    __shared__ unsigned char flag_s[512];     // 0 settled, 1 typ1, 2 typ2
    __shared__ unsigned listA[512];           // (tl<<20)|(e1<<10)|e2
    __shared__ unsigned short listB[512];     // tl of typ2 tokens
    __shared__ int cntA, cntB, gbaseS;
    __shared__ int hist[N_E];
    __shared__ double wred[16], dredA[16];

    const int tid  = threadIdx.x;
    const int lane = tid & 63;
    const int wid  = tid >> 6;
    const int col  = lane & 15;
    const int quad = lane >> 4;
    const int blk_tok0 = blockIdx.x * 512;
    const int wave_tok0 = blk_tok0 + wid * 32;

    if (tid == 0) { cntA = 0; cntB = 0; }
    hist[tid] = 0;

    // z fragment loads first (HBM latency overlaps frag phase)
    float4 zl[2][4];
#pragma unroll
    for (int m = 0; m < 2; ++m) {
        const float* zr = z + (size_t)(wave_tok0 + m * 16 + col) * E_DIM + quad * 8;
#pragma unroll
        for (int kc = 0; kc < 2; ++kc) {
            zl[m][kc * 2]     = *(const float4*)(zr + kc * 32);
            zl[m][kc * 2 + 1] = *(const float4*)(zr + kc * 32 + 4);
        }
    }

    // frag: COALESCED cb read, scattered 8B LDS write (R6-R8 validated map).
    {
        const float4* cb4 = (const float4*)cb;
#pragma unroll
        for (int r = 0; r < 16; ++r) {
            const int ft = r * 1024 + tid;
            const float4 v = cb4[ft];
            const int code = ft >> 4;
            const int k0   = (ft & 15) * 4;
            const int cc = ((code >> 4) << 1) | (k0 >> 5);
            const int l  = (((k0 >> 3) & 3) << 4) | (code & 15);
            const int dst = (cc << 9) | (l << 3) | (k0 & 7);
            union { _Float16 h[4]; uint2 u; } pk;
            pk.h[0] = (_Float16)(v.x * 1024.0f);
            pk.h[1] = (_Float16)(v.y * 1024.0f);
            pk.h[2] = (_Float16)(v.z * 1024.0f);
            pk.h[3] = (_Float16)(v.w * 1024.0f);
            *(uint2*)(sbuf + dst * 2) = pk.u;
        }
    }

    // block 0: exact f32 c2 for the scan kernel (validated frag_kernel order)
    if (blockIdx.x == 0) {
        const float* p = cb + (size_t)tid * E_DIM;
        double s = 0.0;
#pragma unroll
        for (int k = 0; k < E_DIM; ++k) {
            double c = (double)p[k];
            s = fma(c, c, s);
        }
        c2g[tid] = (float)s;
    }
    __syncthreads();   // frags visible

    // c2s from LDS frags (R6-R8 validated; fp16 precision, error << margin)
    {
        const int code = tid;
        const int cc0 = (code >> 4) << 1;
        const int c15 = code & 15;
        float s = 0.f;
#pragma unroll
        for (int half = 0; half < 2; ++half)
#pragma unroll
            for (int lv = 0; lv < 4; ++lv) {
                const int off = (((cc0 + half) << 9) |
                                 (((lv << 4) | c15) << 3)) * 2;
                union { uint4 u; _Float16 h[8]; } b;
                b.u = *(const uint4*)(sbuf + off);
#pragma unroll
                for (int j = 0; j < 8; ++j) {
                    float f = (float)b.h[j];
                    s = fmaf(f, f, s);
                }
            }
        union { _Float16 h; unsigned short u; } q;
        q.h = (_Float16)(s * (-1.0f / 2048.0f));
        c2s[tid] = q.u;
    }

    // A fragments
    f16x8 Ah[2][2];
#pragma unroll
    for (int m = 0; m < 2; ++m)
#pragma unroll
        for (int kc = 0; kc < 2; ++kc) {
            float4 u0 = zl[m][kc * 2], u1 = zl[m][kc * 2 + 1];
            f16x8 a;
            a[0] = (_Float16)u0.x; a[1] = (_Float16)u0.y;
            a[2] = (_Float16)u0.z; a[3] = (_Float16)u0.w;
            a[4] = (_Float16)u1.x; a[5] = (_Float16)u1.y;
            a[6] = (_Float16)u1.z; a[7] = (_Float16)u1.w;
            Ah[m][kc] = a;
        }

    // top-3 packed-key MAX tracker
    unsigned k1[2][4], k2[2][4], k3[2][4];
#pragma unroll
    for (int m = 0; m < 2; ++m)
#pragma unroll
        for (int r = 0; r < 4; ++r) { k1[m][r] = 0u; k2[m][r] = 0u; k3[m][r] = 0u; }

    __syncthreads();   // c2s complete

    // sweep: u'' = 1024*dot - 512*c2 + 64 > 0; key = (bits&~63)|(63-cl)
#pragma unroll 4
    for (int cl = 0; cl < 64; ++cl) {
        const unsigned char* bp = sbuf + cl * 2048 + lane * 16;
        union { uint4 u; f16x8 v; } b0, b1;
        b0.u = *(const uint4*)(bp);
        b1.u = *(const uint4*)(bp + 1024);
        union { unsigned short us; _Float16 h; } cv;
        cv.us = c2s[cl * 16 + col];
        const float ch = 64.0f + (float)cv.h;
        const f32x4 cinit = {ch, ch, ch, ch};
        const unsigned ctag = (unsigned)(63 - cl);
#pragma unroll
        for (int m = 0; m < 2; ++m) {
            f32x4 acc = __builtin_amdgcn_mfma_f32_16x16x32_f16(
                Ah[m][0], b0.v, cinit, 0, 0, 0);
            acc = __builtin_amdgcn_mfma_f32_16x16x32_f16(
                Ah[m][1], b1.v, acc, 0, 0, 0);
#pragma unroll
            for (int r = 0; r < 4; ++r) {
                unsigned key = (__float_as_uint(acc[r]) & 0xFFFFFFC0u) | ctag;
                unsigned t1 = min(k1[m][r], key);
                k3[m][r] = med3u(k2[m][r], k3[m][r], t1);
                k2[m][r] = med3u(k1[m][r], k2[m][r], key);
                k1[m][r] = max(k1[m][r], key);
            }
        }
    }

    // merge + route (validated R4-R8); typ2 -> LDS listB (cap 512 structural)
#pragma unroll 1
    for (int m = 0; m < 2; ++m) {
#pragma unroll 1
        for (int r = 0; r < 4; ++r) {
            const unsigned l1 = k1[m][r], l2 = k2[m][r], l3 = k3[m][r];
            unsigned g1 = l1, g2 = l2, g3 = l3;
#pragma unroll
            for (int d = 1; d < 16; d <<= 1) {
                unsigned p1 = __shfl_xor(g1, d, 64);
                unsigned p2 = __shfl_xor(g2, d, 64);
                unsigned p3 = __shfl_xor(g3, d, 64);
                unsigned t1 = min(g1, p1);
                g3 = med3u(g2, g3, t1);
                g2 = med3u(g1, g2, p1);
                g1 = max(g1, p1);
                g3 = med3u(g2, g3, p2);
                g2 = max(g2, p2);
                g3 = med3u(g2, g3, p3);
            }
            u64 bal1 = __ballot((l1 == g1) || (l2 == g1) || (l3 == g1));
            u64 bal2 = __ballot((l1 == g2) || (l2 == g2) || (l3 == g2));
            if (col == 0) {
                const int tl = wid * 32 + m * 16 + quad * 4 + r;
                unsigned m1 = (unsigned)((bal1 >> (quad * 16)) & 0xFFFFu);
                int c1 = __ffs(m1) - 1;
                int bbest = (63 - (int)(g1 & 63u)) * 16 + c1;
                float v1 = __uint_as_float(g1 & 0xFFFFFFC0u);
                float v2 = __uint_as_float(g2 & 0xFFFFFFC0u);
                float v3 = __uint_as_float(g3 & 0xFFFFFFC0u);
                int typ = 0, bsec = 0;
                if (v1 - v2 < margin_u) {
                    if (v1 - v3 < margin_u) typ = 2;
                    else {
                        unsigned m2 = (unsigned)((bal2 >> (quad * 16)) & 0xFFFFu);
                        if (g2 == g1) m2 &= ~(1u << c1);
                        if (__popc(m2) == 1) {
                            bsec = (63 - (int)(g2 & 63u)) * 16 + (__ffs(m2) - 1);
                            typ = 1;
                        } else typ = 2;
                    }
                }
                if (typ == 1) {
                    int pos = atomicAdd(&cntA, 1);
                    listA[pos] = ((unsigned)tl << 20) |
                                 ((unsigned)bbest << 10) | (unsigned)bsec;
                } else if (typ == 2) {
                    int pos = atomicAdd(&cntB, 1);
                    listB[pos] = (unsigned short)tl;
                }
                best_s[tl] = bbest;
                flag_s[tl] = (unsigned char)typ;
            }
        }
    }

    __syncthreads();   // cntB final
    // publish typ2 tokens to the COMPACT global list; init own keysB slots
    if (tid == 0) gbaseS = atomicAdd(wlCnt, cntB);
    __syncthreads();
    if (tid < cntB) {
        const int tl = listB[tid];
        const int gp = gbaseS + tid;
        if (gp < WLCAP) {
            wlB[gp] = blk_tok0 + tl;
            keysB[gp] = ~0ull;
        } else {    // overflow: resolve serially now (P ~ 0)
            best_s[tl] = exact_best_serial2(z, cb, blk_tok0 + tl);
            flag_s[tl] = 0;
        }
    }
    __syncthreads();   // flag/best stable for epilogue

    // settled epilogue: coalesced z_q / loss partials (own-wave tokens only)
    {
        const int sub = lane & 15, grp = lane >> 4;
        double dl = 0.0;
        const float4* zrow = (const float4*)z;
        const float4* crow = (const float4*)cb;
        float4* qrow = (float4*)(out + ZQ_OFF);
#pragma unroll
        for (int p = 0; p < 8; ++p) {
            int tl = wid * 32 + p * 4 + grp;
            if (!flag_s[tl]) {
                int n = blk_tok0 + tl;
                float4 z4 = zrow[(size_t)n * 16 + sub];
                float4 c4 = crow[(size_t)best_s[tl] * 16 + sub];
                float dx = c4.x - z4.x, dy = c4.y - z4.y;
                float dz = c4.z - z4.z, dw = c4.w - z4.w;
                float4 q;
                q.x = z4.x + dx; q.y = z4.y + dy;
                q.z = z4.z + dz; q.w = z4.w + dw;
                qrow[(size_t)n * 16 + sub] = q;
                dl += (double)dx * dx + (double)dy * dy
                    + (double)dz * dz + (double)dw * dw;
            }
        }
#pragma unroll
        for (int off = 32; off > 0; off >>= 1)
            dl += __shfl_down(dl, off, 64);
        if (lane == 0) wred[wid] = dl;
    }
    const int nA = cntA;

    // ---- fix-A: 2-candidate exact, thread-per-entry, FULLY STREAMING ----
    {
        double da = 0.0;
        for (int t = tid; t < nA; t += 1024) {
            const unsigned ent = listA[t];
            const int tl = (int)(ent >> 20);
            const int e1 = (int)((ent >> 10) & 1023u);
            const int e2 = (int)(ent & 1023u);
            const int n  = blk_tok0 + tl;
            const float* zr = z + (size_t)n * E_DIM;
            float r8[8];
#pragma unroll
            for (int j = 0; j < 8; ++j) r8[j] = __fmul_rn(zr[j], zr[j]);
#pragma unroll
            for (int i = 8; i < 64; i += 8)
#pragma unroll
                for (int j = 0; j < 8; ++j)
                    r8[j] = __fadd_rn(r8[j], __fmul_rn(zr[i + j], zr[i + j]));
            float z2 = __fadd_rn(
                __fadd_rn(__fadd_rn(r8[0], r8[1]), __fadd_rn(r8[2], r8[3])),
                __fadd_rn(__fadd_rn(r8[4], r8[5]), __fadd_rn(r8[6], r8[7])));
            u64 bk = ~0ull;
#pragma unroll
            for (int c = 0; c < 2; ++c) {
                const int e = c ? e2 : e1;
                const float* cp = cb + (size_t)e * E_DIM;
                double cs = 0.0, mm = 0.0;
#pragma unroll
                for (int k = 0; k < E_DIM; ++k) {
                    double cc = (double)cp[k];
                    cs = fma(cc, cc, cs);
                    mm = fma((double)zr[k], cc, mm);
                }
                float d = __fsub_rn(__fadd_rn(z2, (float)cs),
                                    __fmul_rn(2.0f, (float)mm));
                u64 key = ((u64)__float_as_uint(d) << 32) | (unsigned)e;
                if (key < bk) bk = key;
            }
            const int best = (int)(bk & 0xffffffffull);
            const float4* cp4 = (const float4*)(cb + (size_t)best * E_DIM);
            const float4* zp4 = (const float4*)zr;
            float4* qp = (float4*)(out + ZQ_OFF + (size_t)n * E_DIM);
            double dd = 0.0;
#pragma unroll
            for (int k = 0; k < 16; ++k) {
                float4 c4 = cp4[k]; float4 zz = zp4[k];
                float dx = c4.x - zz.x, dy = c4.y - zz.y;
                float dz = c4.z - zz.z, dw = c4.w - zz.w;
                float4 q;
                q.x = zz.x + dx; q.y = zz.y + dy;
                q.z = zz.z + dz; q.w = zz.w + dw;
                qp[k] = q;
                dd += (double)dx * dx + (double)dy * dy
                    + (double)dz * dz + (double)dw * dw;
            }
            best_s[tl] = best;
            da += dd;
        }
#pragma unroll
        for (int off = 32; off > 0; off >>= 1)
            da += __shfl_down(da, off, 64);
        if (lane == 0) dredA[wid] = da;
    }

    __syncthreads();   // best_s final (settled + typ1 + overflow)

    // per-block histogram (typ2 excluded; finalize adds them from keysB)
    if (tid < 512 && flag_s[tid] != 2)
        atomicAdd(&hist[best_s[tid]], 1);
    // coalesced idx write (typ2 slots are placeholders, fixed by finalize)
    if (tid < 512)
        out[IDX_OFF + blk_tok0 + tid] = (float)best_s[tid];
    if (tid == 0) {
        double s = 0.0;
#pragma unroll
        for (int i = 0; i < 16; ++i) s += wred[i] + dredA[i];
        slots[blockIdx.x] = s;
    }
    __syncthreads();   // hist complete
    if (hist[tid]) atomicAdd(&counts[tid], hist[tid]);
}

// Dispatch 3: full scan for typ2 tokens — R4's proven compact-list kernel.
// With count~2k only ~32 groups (1024 blocks) do work; rest early-exit.
__global__ __launch_bounds__(64) void fixup_scan(
    const float* __restrict__ z, const float* __restrict__ cb,
    const float* __restrict__ c2, const int* __restrict__ wlB,
    const int* __restrict__ wlCnt, u64* __restrict__ keysB) {

    int count = *wlCnt; if (count > WLCAP) count = WLCAP;
    const int g = blockIdx.x >> 5;
    const int s = blockIdx.x & 31;
    if (g * 64 >= count) return;
    const int lane = threadIdx.x;
    const int w = g * 64 + lane;
    const bool valid = w < count;
    const int n = wlB[valid ? w : g * 64];

    float zf[E_DIM];
    const float4* zp = (const float4*)(z + (size_t)n * E_DIM);
#pragma unroll
    for (int k = 0; k < 16; ++k) {
        float4 v = zp[k];
        zf[4 * k] = v.x; zf[4 * k + 1] = v.y;
        zf[4 * k + 2] = v.z; zf[4 * k + 3] = v.w;
    }
    float r8[8];
#pragma unroll
    for (int j = 0; j < 8; ++j) r8[j] = __fmul_rn(zf[j], zf[j]);
#pragma unroll
    for (int i = 8; i < 64; i += 8)
#pragma unroll
        for (int j = 0; j < 8; ++j)
            r8[j] = __fadd_rn(r8[j], __fmul_rn(zf[i + j], zf[i + j]));
    const float z2 = __fadd_rn(
        __fadd_rn(__fadd_rn(r8[0], r8[1]), __fadd_rn(r8[2], r8[3])),
        __fadd_rn(__fadd_rn(r8[4], r8[5]), __fadd_rn(r8[6], r8[7])));

    const int e0 = s * 32;
    float d32[32];
    float dmin = 1e30f;
#pragma unroll 4
    for (int i = 0; i < 32; ++i) {
        const float* cp = cb + (size_t)(e0 + i) * E_DIM;   // wave-uniform row
        float a0 = 0.f, a1 = 0.f, a2 = 0.f, a3 = 0.f;
#pragma unroll
        for (int k = 0; k < 64; k += 4) {
            a0 = fmaf(zf[k],     cp[k],     a0);
            a1 = fmaf(zf[k + 1], cp[k + 1], a1);
            a2 = fmaf(zf[k + 2], cp[k + 2], a2);
            a3 = fmaf(zf[k + 3], cp[k + 3], a3);
        }
        float d = z2 + c2[e0 + i] - 2.0f * ((a0 + a1) + (a2 + a3));
        d32[i] = d;
        dmin = fminf(dmin, d);
    }
    u64 best = ~0ull;
    const float thr = dmin + 4e-3f;   // R4-validated window
    for (int it = 0; it < 32; ++it) {
        float dm = d32[0]; int am = 0;
#pragma unroll
        for (int i = 1; i < 32; ++i) {
            bool t = d32[i] < dm;
            dm = t ? d32[i] : dm;
            am = t ? i : am;
        }
        bool need = dm <= thr;
        if (!__any(need)) break;
        if (need) {
            int e = e0 + am;
            const float* cp = cb + (size_t)e * E_DIM;
            double mm = 0.0;
#pragma unroll
            for (int i = 0; i < E_DIM; ++i)
                mm = fma((double)zf[i], (double)cp[i], mm);
            float d = __fsub_rn(__fadd_rn(z2, c2[e]),
                                __fmul_rn(2.0f, (float)mm));
            u64 key = ((u64)__float_as_uint(d) << 32) | (unsigned)e;
            if (key < best) best = key;
#pragma unroll
            for (int i = 0; i < 32; ++i)     // static-indexed invalidate
                if (i == am) d32[i] = 1e30f;
        }
    }
    if (valid && best != ~0ull) atomicMin(&keysB[w], best);
}

// Dispatch 4: apply typ2 (streaming over the compact list), add their bins
// to the histogram, entropy + mse. NO full-idx re-read (that was ~70us).
__global__ __launch_bounds__(1024) void finalize4(
    const float* __restrict__ z, const float* __restrict__ cb,
    const int* __restrict__ wlB, const int* __restrict__ wlCnt,
    const u64* __restrict__ keysB, const int* __restrict__ counts,
    const double* __restrict__ slots, float* __restrict__ out) {

    __shared__ int hist[N_E];
    __shared__ double red[1024];
    __shared__ double ssq_s;
    const int tid = threadIdx.x;
    hist[tid] = 0;
    __syncthreads();

    int count = *wlCnt; if (count > WLCAP) count = WLCAP;
    double myss = 0.0;
    for (int w = tid; w < count; w += 1024) {
        const int n = wlB[w];
        const int best = (int)(keysB[w] & 0xffffffffull);
        const float4* cp4 = (const float4*)(cb + (size_t)best * E_DIM);
        const float4* zp4 = (const float4*)(z + (size_t)n * E_DIM);
        float4* qp = (float4*)(out + ZQ_OFF + (size_t)n * E_DIM);
        double dd = 0.0;
#pragma unroll
        for (int k = 0; k < 16; ++k) {
            float4 c4 = cp4[k]; float4 zz = zp4[k];
            float dx = c4.x - zz.x, dy = c4.y - zz.y;
            float dz = c4.z - zz.z, dw = c4.w - zz.w;
            float4 q;
            q.x = zz.x + dx; q.y = zz.y + dy;
            q.z = zz.z + dz; q.w = zz.w + dw;
            qp[k] = q;
            dd += (double)dx * dx + (double)dy * dy
                + (double)dz * dz + (double)dw * dw;
        }
        out[IDX_OFF + n] = (float)best;
        atomicAdd(&hist[best], 1);
        myss += dd;
    }

    red[tid] = myss + (tid < 256 ? slots[tid] : 0.0);
    __syncthreads();
    for (int s = 512; s > 0; s >>= 1) {
        if (tid < s) red[tid] += red[tid + s];
        __syncthreads();
    }
    if (tid == 0) ssq_s = red[0];
    __syncthreads();

    double em = (double)(counts[tid] + hist[tid]) / (double)N_TOK;
    red[tid] = -em * log(em + 1e-10);
    __syncthreads();
    for (int s = 512; s > 0; s >>= 1) {
        if (tid < s) red[tid] += red[tid + s];
        __syncthreads();
    }
    if (tid == 0) {
        double usage = red[0];
        double mse = ssq_s / (double)((size_t)N_TOK * E_DIM);
        out[LOSS_OFF] = (float)((1.0 + BETA) * mse + 0.01 * usage);
        out[PERP_OFF] = (float)exp(usage);
    }
}

extern "C" void kernel_launch(void* const* d_in, const int* in_sizes, int n_in,
                              void* d_out, int out_size, void* d_ws, size_t ws_size,
                              hipStream_t stream) {
    const float* z  = (const float*)d_in[0];
    const float* cb = (const float*)d_in[1];
    float* out = (float*)d_out;

    double* slots  = (double*)((char*)d_ws + WS_SLOTS);
    float*  c2g    = (float*)((char*)d_ws + WS_C2);
    int*    counts = (int*)((char*)d_ws + WS_CNT);
    int*    wlCnt  = (int*)((char*)d_ws + WS_WLC);
    int*    wlB    = (int*)((char*)d_ws + WS_WLB);
    u64*    keysB  = (u64*)((char*)d_ws + WS_KEYSB);

    // zero counts (4KB) + wlCnt (4B, contiguous) in one async memset
    hipMemsetAsync((char*)d_ws + WS_CNT, 0, 4100, stream);

    // u''-space margin 0.071 validated rounds 1-8 (absmax 0 throughout).
    vq_all<<<256, 1024, 0, stream>>>(z, cb, slots, c2g, counts, wlCnt,
                                     wlB, keysB, 0.071f, out);
    fixup_scan<<<4096, 64, 0, stream>>>(z, cb, c2g, wlB, wlCnt, keysB);
    finalize4<<<1, 1024, 0, stream>>>(z, cb, wlB, wlCnt, keysB, counts,
                                      slots, out);
}

// Round 10
// 188.076 us; speedup vs baseline: 4.5688x; 1.0217x over previous
//
#include <hip/hip_runtime.h>
#include <math.h>

#define N_TOK 131072
#define N_E   1024
#define E_DIM 64
#define BETA  0.4

// d_out layout (float32, concatenated in return order):
#define ZQ_OFF   0
#define LOSS_OFF 8388608
#define IDX_OFF  8388609
#define PERP_OFF 8519681

// d_ws layout (107 KB of the >=532 KB proven workspace).
#define WS_SLOTS 0        // 320 doubles: 256 vq_all partials + 64 apply partials
#define WS_C2    2560     // 1024 f32: RN32(exact ||c_e||^2), by vq_all block 0
#define WS_CNT   6656     // 1024 i32 global counts (memset to 0)
#define WS_WLC   10752    // i32 global typ2 count (memset with counts)
#define WS_WLB   10768    // 8192 ints: COMPACT typ2 token list
#define WS_KEYSB 43536    // 8192 u64: packed (d_bits<<32)|e per compact slot
#define WLCAP    8192

typedef _Float16 f16x8 __attribute__((ext_vector_type(8)));
typedef float f32x4  __attribute__((ext_vector_type(4)));
typedef unsigned long long u64;

__device__ __forceinline__ unsigned med3u(unsigned a, unsigned b, unsigned c) {
    unsigned d;
    asm("v_med3_u32 %0, %1, %2, %3" : "=v"(d) : "v"(a), "v"(b), "v"(c));
    return d;
}

// Cold path (global typ2 overflow only, P~0 at cap 8192 vs ~2k expected).
__device__ __attribute__((noinline)) int exact_best_serial2(
    const float* __restrict__ z, const float* __restrict__ cb, int n) {
    const float* zr = z + (size_t)n * E_DIM;
    float r8[8];
#pragma unroll
    for (int j = 0; j < 8; ++j) r8[j] = __fmul_rn(zr[j], zr[j]);
#pragma unroll 1
    for (int i = 8; i < 64; i += 8)
#pragma unroll
        for (int j = 0; j < 8; ++j)
            r8[j] = __fadd_rn(r8[j], __fmul_rn(zr[i + j], zr[i + j]));
    float z2 = __fadd_rn(__fadd_rn(__fadd_rn(r8[0], r8[1]), __fadd_rn(r8[2], r8[3])),
                         __fadd_rn(__fadd_rn(r8[4], r8[5]), __fadd_rn(r8[6], r8[7])));
    u64 bestkey = ~0ull;
#pragma unroll 1
    for (int e = 0; e < N_E; ++e) {
        const float* cp = cb + (size_t)e * E_DIM;
        double cs = 0.0, mm = 0.0;
#pragma unroll 1
        for (int i = 0; i < E_DIM; ++i) {
            double cc = (double)cp[i];
            cs = fma(cc, cc, cs);
            mm = fma((double)zr[i], cc, mm);
        }
        float d = __fsub_rn(__fadd_rn(z2, (float)cs), __fmul_rn(2.0f, (float)mm));
        u64 key = ((u64)__float_as_uint(d) << 32) | (unsigned)e;
        if (key < bestkey) bestkey = key;
    }
    return (int)(bestkey & 0xffffffffu);
}

// Dispatch 2 of 5: R9-validated kernel, byte-for-byte (87us, passed).
__global__ __launch_bounds__(1024, 4) void vq_all(
    const float* __restrict__ z, const float* __restrict__ cb,
    double* __restrict__ slots, float* __restrict__ c2g,
    int* __restrict__ counts, int* __restrict__ wlCnt,
    int* __restrict__ wlB, u64* __restrict__ keysB,
    float margin_u, float* __restrict__ out) {

    __shared__ __align__(16) unsigned char sbuf[131072];
    __shared__ __align__(8)  unsigned short c2s[N_E];
    __shared__ int   best_s[512];
    __shared__ unsigned char flag_s[512];     // 0 settled, 1 typ1, 2 typ2
    __shared__ unsigned listA[512];           // (tl<<20)|(e1<<10)|e2
    __shared__ unsigned short listB[512];     // tl of typ2 tokens
    __shared__ int cntA, cntB, gbaseS;
    __shared__ int hist[N_E];
    __shared__ double wred[16], dredA[16];

    const int tid  = threadIdx.x;
    const int lane = tid & 63;
    const int wid  = tid >> 6;
    const int col  = lane & 15;
    const int quad = lane >> 4;
    const int blk_tok0 = blockIdx.x * 512;
    const int wave_tok0 = blk_tok0 + wid * 32;

    if (tid == 0) { cntA = 0; cntB = 0; }
    hist[tid] = 0;

    // z fragment loads first (HBM latency overlaps frag phase)
    float4 zl[2][4];
#pragma unroll
    for (int m = 0; m < 2; ++m) {
        const float* zr = z + (size_t)(wave_tok0 + m * 16 + col) * E_DIM + quad * 8;
#pragma unroll
        for (int kc = 0; kc < 2; ++kc) {
            zl[m][kc * 2]     = *(const float4*)(zr + kc * 32);
            zl[m][kc * 2 + 1] = *(const float4*)(zr + kc * 32 + 4);
        }
    }

    // frag: COALESCED cb read, scattered 8B LDS write (R6-R9 validated map).
    {
        const float4* cb4 = (const float4*)cb;
#pragma unroll
        for (int r = 0; r < 16; ++r) {
            const int ft = r * 1024 + tid;
            const float4 v = cb4[ft];
            const int code = ft >> 4;
            const int k0   = (ft & 15) * 4;
            const int cc = ((code >> 4) << 1) | (k0 >> 5);
            const int l  = (((k0 >> 3) & 3) << 4) | (code & 15);
            const int dst = (cc << 9) | (l << 3) | (k0 & 7);
            union { _Float16 h[4]; uint2 u; } pk;
            pk.h[0] = (_Float16)(v.x * 1024.0f);
            pk.h[1] = (_Float16)(v.y * 1024.0f);
            pk.h[2] = (_Float16)(v.z * 1024.0f);
            pk.h[3] = (_Float16)(v.w * 1024.0f);
            *(uint2*)(sbuf + dst * 2) = pk.u;
        }
    }

    // block 0: exact f32 c2 for the scan kernel (validated frag_kernel order)
    if (blockIdx.x == 0) {
        const float* p = cb + (size_t)tid * E_DIM;
        double s = 0.0;
#pragma unroll
        for (int k = 0; k < E_DIM; ++k) {
            double c = (double)p[k];
            s = fma(c, c, s);
        }
        c2g[tid] = (float)s;
    }
    __syncthreads();   // frags visible

    // c2s from LDS frags (R6-R9 validated; fp16 precision, error << margin)
    {
        const int code = tid;
        const int cc0 = (code >> 4) << 1;
        const int c15 = code & 15;
        float s = 0.f;
#pragma unroll
        for (int half = 0; half < 2; ++half)
#pragma unroll
            for (int lv = 0; lv < 4; ++lv) {
                const int off = (((cc0 + half) << 9) |
                                 (((lv << 4) | c15) << 3)) * 2;
                union { uint4 u; _Float16 h[8]; } b;
                b.u = *(const uint4*)(sbuf + off);
#pragma unroll
                for (int j = 0; j < 8; ++j) {
                    float f = (float)b.h[j];
                    s = fmaf(f, f, s);
                }
            }
        union { _Float16 h; unsigned short u; } q;
        q.h = (_Float16)(s * (-1.0f / 2048.0f));
        c2s[tid] = q.u;
    }

    // A fragments
    f16x8 Ah[2][2];
#pragma unroll
    for (int m = 0; m < 2; ++m)
#pragma unroll
        for (int kc = 0; kc < 2; ++kc) {
            float4 u0 = zl[m][kc * 2], u1 = zl[m][kc * 2 + 1];
            f16x8 a;
            a[0] = (_Float16)u0.x; a[1] = (_Float16)u0.y;
            a[2] = (_Float16)u0.z; a[3] = (_Float16)u0.w;
            a[4] = (_Float16)u1.x; a[5] = (_Float16)u1.y;
            a[6] = (_Float16)u1.z; a[7] = (_Float16)u1.w;
            Ah[m][kc] = a;
        }

    // top-3 packed-key MAX tracker
    unsigned k1[2][4], k2[2][4], k3[2][4];
#pragma unroll
    for (int m = 0; m < 2; ++m)
#pragma unroll
        for (int r = 0; r < 4; ++r) { k1[m][r] = 0u; k2[m][r] = 0u; k3[m][r] = 0u; }

    __syncthreads();   // c2s complete

    // sweep: u'' = 1024*dot - 512*c2 + 64 > 0; key = (bits&~63)|(63-cl)
#pragma unroll 4
    for (int cl = 0; cl < 64; ++cl) {
        const unsigned char* bp = sbuf + cl * 2048 + lane * 16;
        union { uint4 u; f16x8 v; } b0, b1;
        b0.u = *(const uint4*)(bp);
        b1.u = *(const uint4*)(bp + 1024);
        union { unsigned short us; _Float16 h; } cv;
        cv.us = c2s[cl * 16 + col];
        const float ch = 64.0f + (float)cv.h;
        const f32x4 cinit = {ch, ch, ch, ch};
        const unsigned ctag = (unsigned)(63 - cl);
#pragma unroll
        for (int m = 0; m < 2; ++m) {
            f32x4 acc = __builtin_amdgcn_mfma_f32_16x16x32_f16(
                Ah[m][0], b0.v, cinit, 0, 0, 0);
            acc = __builtin_amdgcn_mfma_f32_16x16x32_f16(
                Ah[m][1], b1.v, acc, 0, 0, 0);
#pragma unroll
            for (int r = 0; r < 4; ++r) {
                unsigned key = (__float_as_uint(acc[r]) & 0xFFFFFFC0u) | ctag;
                unsigned t1 = min(k1[m][r], key);
                k3[m][r] = med3u(k2[m][r], k3[m][r], t1);
                k2[m][r] = med3u(k1[m][r], k2[m][r], key);
                k1[m][r] = max(k1[m][r], key);
            }
        }
    }

    // merge + route (validated R4-R9); typ2 -> LDS listB (cap 512 structural)
#pragma unroll 1
    for (int m = 0; m < 2; ++m) {
#pragma unroll 1
        for (int r = 0; r < 4; ++r) {
            const unsigned l1 = k1[m][r], l2 = k2[m][r], l3 = k3[m][r];
            unsigned g1 = l1, g2 = l2, g3 = l3;
#pragma unroll
            for (int d = 1; d < 16; d <<= 1) {
                unsigned p1 = __shfl_xor(g1, d, 64);
                unsigned p2 = __shfl_xor(g2, d, 64);
                unsigned p3 = __shfl_xor(g3, d, 64);
                unsigned t1 = min(g1, p1);
                g3 = med3u(g2, g3, t1);
                g2 = med3u(g1, g2, p1);
                g1 = max(g1, p1);
                g3 = med3u(g2, g3, p2);
                g2 = max(g2, p2);
                g3 = med3u(g2, g3, p3);
            }
            u64 bal1 = __ballot((l1 == g1) || (l2 == g1) || (l3 == g1));
            u64 bal2 = __ballot((l1 == g2) || (l2 == g2) || (l3 == g2));
            if (col == 0) {
                const int tl = wid * 32 + m * 16 + quad * 4 + r;
                unsigned m1 = (unsigned)((bal1 >> (quad * 16)) & 0xFFFFu);
                int c1 = __ffs(m1) - 1;
                int bbest = (63 - (int)(g1 & 63u)) * 16 + c1;
                float v1 = __uint_as_float(g1 & 0xFFFFFFC0u);
                float v2 = __uint_as_float(g2 & 0xFFFFFFC0u);
                float v3 = __uint_as_float(g3 & 0xFFFFFFC0u);
                int typ = 0, bsec = 0;
                if (v1 - v2 < margin_u) {
                    if (v1 - v3 < margin_u) typ = 2;
                    else {
                        unsigned m2 = (unsigned)((bal2 >> (quad * 16)) & 0xFFFFu);
                        if (g2 == g1) m2 &= ~(1u << c1);
                        if (__popc(m2) == 1) {
                            bsec = (63 - (int)(g2 & 63u)) * 16 + (__ffs(m2) - 1);
                            typ = 1;
                        } else typ = 2;
                    }
                }
                if (typ == 1) {
                    int pos = atomicAdd(&cntA, 1);
                    listA[pos] = ((unsigned)tl << 20) |
                                 ((unsigned)bbest << 10) | (unsigned)bsec;
                } else if (typ == 2) {
                    int pos = atomicAdd(&cntB, 1);
                    listB[pos] = (unsigned short)tl;
                }
                best_s[tl] = bbest;
                flag_s[tl] = (unsigned char)typ;
            }
        }
    }

    __syncthreads();   // cntB final
    // publish typ2 tokens to the COMPACT global list; init own keysB slots
    if (tid == 0) gbaseS = atomicAdd(wlCnt, cntB);
    __syncthreads();
    if (tid < cntB) {
        const int tl = listB[tid];
        const int gp = gbaseS + tid;
        if (gp < WLCAP) {
            wlB[gp] = blk_tok0 + tl;
            keysB[gp] = ~0ull;
        } else {    // overflow: resolve serially now (P ~ 0)
            best_s[tl] = exact_best_serial2(z, cb, blk_tok0 + tl);
            flag_s[tl] = 0;
        }
    }
    __syncthreads();   // flag/best stable for epilogue

    // settled epilogue: coalesced z_q / loss partials (own-wave tokens only)
    {
        const int sub = lane & 15, grp = lane >> 4;
        double dl = 0.0;
        const float4* zrow = (const float4*)z;
        const float4* crow = (const float4*)cb;
        float4* qrow = (float4*)(out + ZQ_OFF);
#pragma unroll
        for (int p = 0; p < 8; ++p) {
            int tl = wid * 32 + p * 4 + grp;
            if (!flag_s[tl]) {
                int n = blk_tok0 + tl;
                float4 z4 = zrow[(size_t)n * 16 + sub];
                float4 c4 = crow[(size_t)best_s[tl] * 16 + sub];
                float dx = c4.x - z4.x, dy = c4.y - z4.y;
                float dz = c4.z - z4.z, dw = c4.w - z4.w;
                float4 q;
                q.x = z4.x + dx; q.y = z4.y + dy;
                q.z = z4.z + dz; q.w = z4.w + dw;
                qrow[(size_t)n * 16 + sub] = q;
                dl += (double)dx * dx + (double)dy * dy
                    + (double)dz * dz + (double)dw * dw;
            }
        }
#pragma unroll
        for (int off = 32; off > 0; off >>= 1)
            dl += __shfl_down(dl, off, 64);
        if (lane == 0) wred[wid] = dl;
    }
    const int nA = cntA;

    // ---- fix-A: 2-candidate exact, thread-per-entry, FULLY STREAMING ----
    {
        double da = 0.0;
        for (int t = tid; t < nA; t += 1024) {
            const unsigned ent = listA[t];
            const int tl = (int)(ent >> 20);
            const int e1 = (int)((ent >> 10) & 1023u);
            const int e2 = (int)(ent & 1023u);
            const int n  = blk_tok0 + tl;
            const float* zr = z + (size_t)n * E_DIM;
            float r8[8];
#pragma unroll
            for (int j = 0; j < 8; ++j) r8[j] = __fmul_rn(zr[j], zr[j]);
#pragma unroll
            for (int i = 8; i < 64; i += 8)
#pragma unroll
                for (int j = 0; j < 8; ++j)
                    r8[j] = __fadd_rn(r8[j], __fmul_rn(zr[i + j], zr[i + j]));
            float z2 = __fadd_rn(
                __fadd_rn(__fadd_rn(r8[0], r8[1]), __fadd_rn(r8[2], r8[3])),
                __fadd_rn(__fadd_rn(r8[4], r8[5]), __fadd_rn(r8[6], r8[7])));
            u64 bk = ~0ull;
#pragma unroll
            for (int c = 0; c < 2; ++c) {
                const int e = c ? e2 : e1;
                const float* cp = cb + (size_t)e * E_DIM;
                double cs = 0.0, mm = 0.0;
#pragma unroll
                for (int k = 0; k < E_DIM; ++k) {
                    double cc = (double)cp[k];
                    cs = fma(cc, cc, cs);
                    mm = fma((double)zr[k], cc, mm);
                }
                float d = __fsub_rn(__fadd_rn(z2, (float)cs),
                                    __fmul_rn(2.0f, (float)mm));
                u64 key = ((u64)__float_as_uint(d) << 32) | (unsigned)e;
                if (key < bk) bk = key;
            }
            const int best = (int)(bk & 0xffffffffull);
            const float4* cp4 = (const float4*)(cb + (size_t)best * E_DIM);
            const float4* zp4 = (const float4*)zr;
            float4* qp = (float4*)(out + ZQ_OFF + (size_t)n * E_DIM);
            double dd = 0.0;
#pragma unroll
            for (int k = 0; k < 16; ++k) {
                float4 c4 = cp4[k]; float4 zz = zp4[k];
                float dx = c4.x - zz.x, dy = c4.y - zz.y;
                float dz = c4.z - zz.z, dw = c4.w - zz.w;
                float4 q;
                q.x = zz.x + dx; q.y = zz.y + dy;
                q.z = zz.z + dz; q.w = zz.w + dw;
                qp[k] = q;
                dd += (double)dx * dx + (double)dy * dy
                    + (double)dz * dz + (double)dw * dw;
            }
            best_s[tl] = best;
            da += dd;
        }
#pragma unroll
        for (int off = 32; off > 0; off >>= 1)
            da += __shfl_down(da, off, 64);
        if (lane == 0) dredA[wid] = da;
    }

    __syncthreads();   // best_s final (settled + typ1 + overflow)

    // per-block histogram (typ2 excluded; apply_typ2 adds them later)
    if (tid < 512 && flag_s[tid] != 2)
        atomicAdd(&hist[best_s[tid]], 1);
    // coalesced idx write (typ2 slots are placeholders, fixed by apply_typ2)
    if (tid < 512)
        out[IDX_OFF + blk_tok0 + tid] = (float)best_s[tid];
    if (tid == 0) {
        double s = 0.0;
#pragma unroll
        for (int i = 0; i < 16; ++i) s += wred[i] + dredA[i];
        slots[blockIdx.x] = s;
    }
    __syncthreads();   // hist complete
    if (hist[tid]) atomicAdd(&counts[tid], hist[tid]);
}

// Dispatch 3: full scan for typ2 tokens — R4/R9's proven compact-list kernel.
__global__ __launch_bounds__(64) void fixup_scan(
    const float* __restrict__ z, const float* __restrict__ cb,
    const float* __restrict__ c2, const int* __restrict__ wlB,
    const int* __restrict__ wlCnt, u64* __restrict__ keysB) {

    int count = *wlCnt; if (count > WLCAP) count = WLCAP;
    const int g = blockIdx.x >> 5;
    const int s = blockIdx.x & 31;
    if (g * 64 >= count) return;
    const int lane = threadIdx.x;
    const int w = g * 64 + lane;
    const bool valid = w < count;
    const int n = wlB[valid ? w : g * 64];

    float zf[E_DIM];
    const float4* zp = (const float4*)(z + (size_t)n * E_DIM);
#pragma unroll
    for (int k = 0; k < 16; ++k) {
        float4 v = zp[k];
        zf[4 * k] = v.x; zf[4 * k + 1] = v.y;
        zf[4 * k + 2] = v.z; zf[4 * k + 3] = v.w;
    }
    float r8[8];
#pragma unroll
    for (int j = 0; j < 8; ++j) r8[j] = __fmul_rn(zf[j], zf[j]);
#pragma unroll
    for (int i = 8; i < 64; i += 8)
#pragma unroll
        for (int j = 0; j < 8; ++j)
            r8[j] = __fadd_rn(r8[j], __fmul_rn(zf[i + j], zf[i + j]));
    const float z2 = __fadd_rn(
        __fadd_rn(__fadd_rn(r8[0], r8[1]), __fadd_rn(r8[2], r8[3])),
        __fadd_rn(__fadd_rn(r8[4], r8[5]), __fadd_rn(r8[6], r8[7])));

    const int e0 = s * 32;
    float d32[32];
    float dmin = 1e30f;
#pragma unroll 4
    for (int i = 0; i < 32; ++i) {
        const float* cp = cb + (size_t)(e0 + i) * E_DIM;   // wave-uniform row
        float a0 = 0.f, a1 = 0.f, a2 = 0.f, a3 = 0.f;
#pragma unroll
        for (int k = 0; k < 64; k += 4) {
            a0 = fmaf(zf[k],     cp[k],     a0);
            a1 = fmaf(zf[k + 1], cp[k + 1], a1);
            a2 = fmaf(zf[k + 2], cp[k + 2], a2);
            a3 = fmaf(zf[k + 3], cp[k + 3], a3);
        }
        float d = z2 + c2[e0 + i] - 2.0f * ((a0 + a1) + (a2 + a3));
        d32[i] = d;
        dmin = fminf(dmin, d);
    }
    u64 best = ~0ull;
    const float thr = dmin + 4e-3f;   // R4-validated window
    for (int it = 0; it < 32; ++it) {
        float dm = d32[0]; int am = 0;
#pragma unroll
        for (int i = 1; i < 32; ++i) {
            bool t = d32[i] < dm;
            dm = t ? d32[i] : dm;
            am = t ? i : am;
        }
        bool need = dm <= thr;
        if (!__any(need)) break;
        if (need) {
            int e = e0 + am;
            const float* cp = cb + (size_t)e * E_DIM;
            double mm = 0.0;
#pragma unroll
            for (int i = 0; i < E_DIM; ++i)
                mm = fma((double)zf[i], (double)cp[i], mm);
            float d = __fsub_rn(__fadd_rn(z2, c2[e]),
                                __fmul_rn(2.0f, (float)mm));
            u64 key = ((u64)__float_as_uint(d) << 32) | (unsigned)e;
            if (key < best) best = key;
#pragma unroll
            for (int i = 0; i < 32; ++i)     // static-indexed invalidate
                if (i == am) d32[i] = 1e30f;
        }
    }
    if (valid && best != ~0ull) atomicMin(&keysB[w], best);
}

// Dispatch 4: apply typ2 results in PARALLEL (was inside single-block
// finalize — one CU streaming ~2MB while 255 idle, ~35us). One wave per
// token, 64 blocks; per-block sum_sq partial into always-written slot.
__global__ __launch_bounds__(256) void apply_typ2(
    const float* __restrict__ z, const float* __restrict__ cb,
    const int* __restrict__ wlB, const int* __restrict__ wlCnt,
    const u64* __restrict__ keysB, int* __restrict__ counts,
    double* __restrict__ slots, float* __restrict__ out) {

    __shared__ double part[4];
    int count = *wlCnt; if (count > WLCAP) count = WLCAP;
    const int lane = threadIdx.x & 63;
    const int lw   = threadIdx.x >> 6;
    double acc = 0.0;
    for (int w = blockIdx.x * 4 + lw; w < count; w += 256) {
        const int n = wlB[w];
        const int best = (int)(keysB[w] & 0xffffffffull);
        float cv = cb[(size_t)best * E_DIM + lane];
        float zi = z[(size_t)n * E_DIM + lane];
        float diff = cv - zi;
        out[ZQ_OFF + (size_t)n * E_DIM + lane] = zi + diff;
        double d2 = (double)diff * (double)diff;
#pragma unroll
        for (int off = 32; off > 0; off >>= 1)
            d2 += __shfl_down(d2, off, 64);
        if (lane == 0) {
            acc += d2;
            atomicAdd(&counts[best], 1);
            out[IDX_OFF + n] = (float)best;
        }
    }
    if (lane == 0) part[lw] = acc;
    __syncthreads();
    if (threadIdx.x == 0)
        slots[256 + blockIdx.x] = part[0] + part[1] + part[2] + part[3];
}

// Dispatch 5: entropy + mse only (no token streaming). Single block, ~3us.
__global__ __launch_bounds__(1024) void finalize5(
    const int* __restrict__ counts, const double* __restrict__ slots,
    float* __restrict__ out) {
    __shared__ double red[1024];
    const int tid = threadIdx.x;
    red[tid] = (tid < 320) ? slots[tid] : 0.0;
    __syncthreads();
    for (int s = 512; s > 0; s >>= 1) {
        if (tid < s) red[tid] += red[tid + s];
        __syncthreads();
    }
    double ssq = red[0];
    __syncthreads();
    double em = (double)counts[tid] / (double)N_TOK;
    red[tid] = -em * log(em + 1e-10);
    __syncthreads();
    for (int s = 512; s > 0; s >>= 1) {
        if (tid < s) red[tid] += red[tid + s];
        __syncthreads();
    }
    if (tid == 0) {
        double usage = red[0];
        double mse = ssq / (double)((size_t)N_TOK * E_DIM);
        out[LOSS_OFF] = (float)((1.0 + BETA) * mse + 0.01 * usage);
        out[PERP_OFF] = (float)exp(usage);
    }
}

extern "C" void kernel_launch(void* const* d_in, const int* in_sizes, int n_in,
                              void* d_out, int out_size, void* d_ws, size_t ws_size,
                              hipStream_t stream) {
    const float* z  = (const float*)d_in[0];
    const float* cb = (const float*)d_in[1];
    float* out = (float*)d_out;

    double* slots  = (double*)((char*)d_ws + WS_SLOTS);
    float*  c2g    = (float*)((char*)d_ws + WS_C2);
    int*    counts = (int*)((char*)d_ws + WS_CNT);
    int*    wlCnt  = (int*)((char*)d_ws + WS_WLC);
    int*    wlB    = (int*)((char*)d_ws + WS_WLB);
    u64*    keysB  = (u64*)((char*)d_ws + WS_KEYSB);

    // zero counts (4KB) + wlCnt (4B, contiguous) in one async memset
    hipMemsetAsync((char*)d_ws + WS_CNT, 0, 4100, stream);

    // u''-space margin 0.071 validated rounds 1-9 (absmax 0 throughout).
    vq_all<<<256, 1024, 0, stream>>>(z, cb, slots, c2g, counts, wlCnt,
                                     wlB, keysB, 0.071f, out);
    fixup_scan<<<4096, 64, 0, stream>>>(z, cb, c2g, wlB, wlCnt, keysB);
    apply_typ2<<<64, 256, 0, stream>>>(z, cb, wlB, wlCnt, keysB, counts,
                                       slots, out);
    finalize5<<<1, 1024, 0, stream>>>(counts, slots, out);
}